// Round 4
// baseline (339.095 us; speedup 1.0000x reference)
//
#include <hip/hip_runtime.h>
#include <hip/hip_bf16.h>

#define HIDDEN 1024
#define NHEAD 16
#define NKV 4
#define HDIM 64
#define KVDIM 256
#define SEQ 2048
#define BATCH 2
#define NQKV 1536   // 1024 (Q) + 256 (K) + 256 (V)

typedef __attribute__((ext_vector_type(4)))  float f32x4;
typedef __attribute__((ext_vector_type(16))) float f32x16;
typedef __attribute__((ext_vector_type(8)))  short s16x8;

#if defined(__has_builtin)
#if __has_builtin(__builtin_amdgcn_exp2f)
#define EXP2F(x) __builtin_amdgcn_exp2f(x)
#else
#define EXP2F(x) exp2f(x)
#endif
#else
#define EXP2F(x) exp2f(x)
#endif

static __device__ __forceinline__ ushort f2bf(float f) {
    union { __hip_bfloat16 b; ushort u; } cv; cv.b = __float2bfloat16(f); return cv.u;
}
static __device__ __forceinline__ float bfu2f(ushort u) {
    union { float f; unsigned int i; } cv; cv.i = ((unsigned int)u) << 16; return cv.f;
}
static __device__ __forceinline__ void split2(float v, ushort& h, ushort& l) {
    h = f2bf(v); l = f2bf(v - bfu2f(h));
}
// round-half-up f32->bf16 (positive, finite inputs only — P values)
static __device__ __forceinline__ ushort f2bf_rh(float f) {
    union { float f; unsigned u; } c; c.f = f;
    return (ushort)((c.u + 0x8000u) >> 16);
}
// async global->LDS, 16B per lane. LDS dest = wave-uniform base + lane*16.
static __device__ __forceinline__ void async16(const void* g, void* l) {
    __builtin_amdgcn_global_load_lds((__attribute__((address_space(1))) void*)g,
                                     (__attribute__((address_space(3))) void*)l, 16, 0, 0);
}

// ---------------------------------------------------------------------------
// X fp32 -> hi/lo bf16 planes (elementwise).
// ---------------------------------------------------------------------------
__global__ __launch_bounds__(256)
void split_x(const float* __restrict__ in, ushort* __restrict__ hi,
             ushort* __restrict__ lo)
{
    int i = blockIdx.x * 256 + threadIdx.x;
    float4 v = ((const float4*)in)[i];
    ushort4 h, l;
    split2(v.x, h.x, l.x); split2(v.y, h.y, l.y);
    split2(v.z, h.z, l.z); split2(v.w, h.w, l.w);
    ((ushort4*)hi)[i] = h;
    ((ushort4*)lo)[i] = l;
}

// ---------------------------------------------------------------------------
// W [K][N] fp32 -> transposed split planes T{hi,lo}[roff+n][k] bf16.
// ---------------------------------------------------------------------------
__global__ __launch_bounds__(256)
void wtrans_split(const float* __restrict__ W, ushort* __restrict__ Thi,
                  ushort* __restrict__ Tlo, int roff, int N, int K)
{
    __shared__ float T[64][65];
    const int n0 = blockIdx.x * 64, k0 = blockIdx.y * 64;
    const int tid = threadIdx.x;
#pragma unroll
    for (int it = 0; it < 4; it++) {
        int idx = tid + it * 256;
        int kk = idx >> 4, n4 = (idx & 15) * 4;
        float4 v = *(const float4*)(W + (size_t)(k0 + kk) * N + n0 + n4);
        T[kk][n4 + 0] = v.x; T[kk][n4 + 1] = v.y;
        T[kk][n4 + 2] = v.z; T[kk][n4 + 3] = v.w;
    }
    __syncthreads();
#pragma unroll
    for (int it = 0; it < 4; it++) {
        int idx = tid + it * 256;
        int n = idx >> 4, k4 = (idx & 15) * 4;
        ushort4 h4, l4;
        split2(T[k4 + 0][n], h4.x, l4.x);
        split2(T[k4 + 1][n], h4.y, l4.y);
        split2(T[k4 + 2][n], h4.z, l4.z);
        split2(T[k4 + 3][n], h4.w, l4.w);
        *(ushort4*)(Thi + (size_t)(roff + n0 + n) * K + k0 + k4) = h4;
        *(ushort4*)(Tlo + (size_t)(roff + n0 + n) * K + k0 + k4) = l4;
    }
}

// ---------------------------------------------------------------------------
// Split-bf16 MFMA GEMM (unchanged structure from round 3).
// MODE 0: bf16 out (QKV; Q cols scaled 0.125*log2e for exp2-domain softmax)
// MODE 1: fp32 out
// ---------------------------------------------------------------------------
template <int MODE>
__global__ __launch_bounds__(256)
void gemm_split(const ushort* __restrict__ Ahi, const ushort* __restrict__ Alo,
                const ushort* __restrict__ Bhi, const ushort* __restrict__ Blo,
                const float* __restrict__ b0, const float* __restrict__ b1,
                const float* __restrict__ b2, void* __restrict__ Cout,
                int M, int N, int K)
{
    __shared__ __align__(16) ushort Ah[128 * 32];
    __shared__ __align__(16) ushort Al[128 * 32];
    __shared__ __align__(16) ushort Bh[128 * 32];
    __shared__ __align__(16) ushort Bl[128 * 32];

    const int tid = threadIdx.x;
    const int lane = tid & 63, wv = tid >> 6;
    const int wr = wv >> 1, wc = wv & 1;
    const int m = lane & 15, c = lane >> 4;
    const int row0 = blockIdx.y * 128, col0 = blockIdx.x * 128;

    const ushort* gA0[2]; const ushort* gA1[2];
    const ushort* gB0[2]; const ushort* gB1[2];
    int ldsOff[2];
#pragma unroll
    for (int it = 0; it < 2; it++) {
        int idx = it * 256 + tid;
        int r = idx >> 2, cb = (idx & 3) * 8;
        gA0[it] = Ahi + (size_t)(row0 + r) * K + cb;
        gA1[it] = Alo + (size_t)(row0 + r) * K + cb;
        gB0[it] = Bhi + (size_t)(col0 + r) * K + cb;
        gB1[it] = Blo + (size_t)(col0 + r) * K + cb;
        ldsOff[it] = (it * 256 + wv * 64) * 8;
    }

    f32x4 acc[4][4];
#pragma unroll
    for (int t = 0; t < 4; t++)
#pragma unroll
        for (int u = 0; u < 4; u++) acc[t][u] = (f32x4){0.f, 0.f, 0.f, 0.f};

    for (int k0 = 0; k0 < K; k0 += 32) {
        __syncthreads();
#pragma unroll
        for (int it = 0; it < 2; it++) {
            async16(gA0[it] + k0, Ah + ldsOff[it]);
            async16(gA1[it] + k0, Al + ldsOff[it]);
            async16(gB0[it] + k0, Bh + ldsOff[it]);
            async16(gB1[it] + k0, Bl + ldsOff[it]);
        }
        __syncthreads();

        s16x8 ah[4], al[4], bh[4], bl[4];
#pragma unroll
        for (int t = 0; t < 4; t++) {
            int ra = (64 * wr + 16 * t + m) * 32 + c * 8;
            int rb = (64 * wc + 16 * t + m) * 32 + c * 8;
            ah[t] = *(const s16x8*)&Ah[ra];
            al[t] = *(const s16x8*)&Al[ra];
            bh[t] = *(const s16x8*)&Bh[rb];
            bl[t] = *(const s16x8*)&Bl[rb];
        }
#pragma unroll
        for (int t = 0; t < 4; t++)
#pragma unroll
            for (int u = 0; u < 4; u++) {
                acc[t][u] = __builtin_amdgcn_mfma_f32_16x16x32_bf16(ah[t], bh[u], acc[t][u], 0, 0, 0);
                acc[t][u] = __builtin_amdgcn_mfma_f32_16x16x32_bf16(ah[t], bl[u], acc[t][u], 0, 0, 0);
                acc[t][u] = __builtin_amdgcn_mfma_f32_16x16x32_bf16(al[t], bh[u], acc[t][u], 0, 0, 0);
            }
    }

    const int orow = row0 + 64 * wr + 4 * c;
    const int ocol = col0 + 64 * wc + m;
    if (MODE == 0) {
        ushort* Cb = (ushort*)Cout;
#pragma unroll
        for (int u = 0; u < 4; u++) {
            int n = ocol + 16 * u;
            float bias, scl;
            if (n < 1024)      { bias = b0[n];        scl = 0.18033688f; }  // 0.125*log2(e)
            else if (n < 1280) { bias = b1[n - 1024]; scl = 1.0f; }
            else               { bias = b2[n - 1280]; scl = 1.0f; }
#pragma unroll
            for (int t = 0; t < 4; t++)
#pragma unroll
                for (int r = 0; r < 4; r++)
                    Cb[(size_t)(orow + 16 * t + r) * N + n] = f2bf((acc[t][u][r] + bias) * scl);
        }
    } else {
        float* Cf = (float*)Cout;
#pragma unroll
        for (int u = 0; u < 4; u++) {
            int n = ocol + 16 * u;
            float bias = b0[n];
#pragma unroll
            for (int t = 0; t < 4; t++)
#pragma unroll
                for (int r = 0; r < 4; r++)
                    Cf[(size_t)(orow + 16 * t + r) * N + n] = acc[t][u][r] + bias;
        }
    }
}

// ---------------------------------------------------------------------------
// V columns of QKV buffer (bf16, stride NQKV) -> Vt [b][hk][d][s] bf16.
// ---------------------------------------------------------------------------
__global__ __launch_bounds__(256)
void vtrans_bf(const ushort* __restrict__ QKV, ushort* __restrict__ Vt)
{
    __shared__ ushort T[64][65];
    const int s0 = blockIdx.x * 64, hk = blockIdx.y, b = blockIdx.z;
    const int tid = threadIdx.x;
#pragma unroll
    for (int it = 0; it < 4; it++) {
        int idx = tid + it * 256;
        int r = idx >> 4, d4 = (idx & 15) * 4;
        ushort4 v = *(const ushort4*)(QKV + (size_t)(b * SEQ + s0 + r) * NQKV + 1280 + hk * HDIM + d4);
        T[r][d4 + 0] = v.x; T[r][d4 + 1] = v.y;
        T[r][d4 + 2] = v.z; T[r][d4 + 3] = v.w;
    }
    __syncthreads();
#pragma unroll
    for (int it = 0; it < 4; it++) {
        int idx = tid + it * 256;
        int d = idx >> 4, s4 = (idx & 15) * 4;
        ushort4 o;
        o.x = T[s4 + 0][d]; o.y = T[s4 + 1][d];
        o.z = T[s4 + 2][d]; o.w = T[s4 + 3][d];
        *(ushort4*)(Vt + ((size_t)((b * NKV + hk) * HDIM + d)) * SEQ + s0 + s4) = o;
    }
}

// ---------------------------------------------------------------------------
// Flash attention v2: 32x32x16 MFMA, kt-split waves, no in-loop barriers.
// Block = 32 q-rows x (head, batch); wave w handles kt = w, w+4, ... (8 tiles).
// No-max softmax in exp2 domain (log2e folded into Q). l via ones-column MFMA.
// K/V fragments loaded direct from global (L2-resident: K cols 2MB + Vt 2MB).
// Per-wave partial O (f32) + l merged once at the end through LDS.
// 32x32 layouts: A/B: m|n=lane&31, k=(lane>>5)*8+j. C/D (verified m74/m101):
// col=lane&31, row=(reg&3)+8*(reg>>2)+4*(lane>>5).
// ---------------------------------------------------------------------------
__global__ __launch_bounds__(256)
void attn_mfma2(const ushort* __restrict__ QKV, const ushort* __restrict__ Vt,
                ushort* __restrict__ Chi, ushort* __restrict__ Clo)
{
    __shared__ __align__(16) ushort Ps[4][32][72];   // per-wave P [q][key]
    __shared__ float OL[4][32][64];                  // per-wave partial O
    __shared__ float LL[4][32];                      // per-wave partial l

    const int tid = threadIdx.x, w = tid >> 6, lane = tid & 63;
    const int n32 = lane & 31, h5 = lane >> 5;
    const int q0 = blockIdx.x * 32, h = blockIdx.y, b = blockIdx.z, hk = h >> 2;

    // Q A-fragments (4 k-chunks of 16), hoisted across the whole loop
    const ushort* qrow = QKV + (size_t)(b * SEQ + q0 + n32) * NQKV + h * HDIM + h5 * 8;
    s16x8 aq[4];
#pragma unroll
    for (int kc = 0; kc < 4; kc++) aq[kc] = *(const s16x8*)(qrow + kc * 16);

    f32x16 accO[2], accl;
#pragma unroll
    for (int j = 0; j < 16; j++) { accO[0][j] = 0.f; accO[1][j] = 0.f; accl[j] = 0.f; }

    s16x8 ones;
#pragma unroll
    for (int j = 0; j < 8; j++) ones[j] = (short)0x3F80;   // bf16 1.0

    const ushort* kbase = QKV + (size_t)(b * SEQ) * NQKV + 1024 + hk * HDIM + h5 * 8;
    const ushort* vbase = Vt + (size_t)((b * NKV + hk) * HDIM) * SEQ + h5 * 8;

    for (int kt = w; kt < SEQ / 64; kt += 4) {
        // --- scores per 32-key tile: S = QK^T (log2-domain), exp2, pack to Ps ---
#pragma unroll
        for (int kn = 0; kn < 2; kn++) {
            const ushort* kr = kbase + (size_t)(kt * 64 + kn * 32 + n32) * NQKV;
            f32x16 S;
#pragma unroll
            for (int j = 0; j < 16; j++) S[j] = 0.f;
#pragma unroll
            for (int kc = 0; kc < 4; kc++) {
                s16x8 kf = *(const s16x8*)(kr + kc * 16);
                S = __builtin_amdgcn_mfma_f32_32x32x16_bf16(aq[kc], kf, S, 0, 0, 0);
            }
#pragma unroll
            for (int reg = 0; reg < 16; reg++) {
                int q = (reg & 3) + 8 * (reg >> 2) + 4 * h5;
                Ps[w][q][kn * 32 + n32] = f2bf_rh(EXP2F(S[reg]));
            }
        }

        // --- P A-fragments (same-wave LDS RAW: DS in-order, no barrier) ---
        s16x8 pa[4];
#pragma unroll
        for (int kc = 0; kc < 4; kc++)
            pa[kc] = *(const s16x8*)&Ps[w][n32][kc * 16 + h5 * 8];

        // --- O += P V ; l += P * 1 ---
#pragma unroll
        for (int kc = 0; kc < 4; kc++) {
            accl = __builtin_amdgcn_mfma_f32_32x32x16_bf16(pa[kc], ones, accl, 0, 0, 0);
#pragma unroll
            for (int dn = 0; dn < 2; dn++) {
                const ushort* vr = vbase + (size_t)(dn * 32 + n32) * SEQ + kt * 64 + kc * 16;
                s16x8 vf = *(const s16x8*)vr;
                accO[dn] = __builtin_amdgcn_mfma_f32_32x32x16_bf16(pa[kc], vf, accO[dn], 0, 0, 0);
            }
        }
    }

    // --- write per-wave partials ---
#pragma unroll
    for (int reg = 0; reg < 16; reg++) {
        int q = (reg & 3) + 8 * (reg >> 2) + 4 * h5;
        OL[w][q][n32]      = accO[0][reg];
        OL[w][q][32 + n32] = accO[1][reg];
        if (n32 == 0) LL[w][q] = accl[reg];
    }
    __syncthreads();

    // --- merge 4 waves, normalize, split-write ctx (8 elements/thread) ---
    {
        const int qq = tid >> 3;           // 0..31
        const int d0 = (tid & 7) * 8;      // 0..56
        float lsum = LL[0][qq] + LL[1][qq] + LL[2][qq] + LL[3][qq];
        float inv = 1.f / lsum;
        ushort4 hs0, hs1, ls0, ls1;
        ushort* hp = &hs0.x; ushort* lp = &ls0.x;
        ushort tmpH[8], tmpL[8];
#pragma unroll
        for (int e = 0; e < 8; e++) {
            float v = (OL[0][qq][d0 + e] + OL[1][qq][d0 + e] +
                       OL[2][qq][d0 + e] + OL[3][qq][d0 + e]) * inv;
            split2(v, tmpH[e], tmpL[e]);
        }
        hs0 = make_ushort4(tmpH[0], tmpH[1], tmpH[2], tmpH[3]);
        hs1 = make_ushort4(tmpH[4], tmpH[5], tmpH[6], tmpH[7]);
        ls0 = make_ushort4(tmpL[0], tmpL[1], tmpL[2], tmpL[3]);
        ls1 = make_ushort4(tmpL[4], tmpL[5], tmpL[6], tmpL[7]);
        (void)hp; (void)lp;
        size_t off = (size_t)(b * SEQ + q0 + qq) * HIDDEN + h * HDIM + d0;
        *(ushort4*)(Chi + off)     = hs0;
        *(ushort4*)(Chi + off + 4) = hs1;
        *(ushort4*)(Clo + off)     = ls0;
        *(ushort4*)(Clo + off + 4) = ls1;
    }
}

// ---------------------------------------------------------------------------
extern "C" void kernel_launch(void* const* d_in, const int* in_sizes, int n_in,
                              void* d_out, int out_size, void* d_ws, size_t ws_size,
                              hipStream_t stream)
{
    const float* X  = (const float*)d_in[0];
    const float* Wq = (const float*)d_in[1];
    const float* bq = (const float*)d_in[2];
    const float* Wk = (const float*)d_in[3];
    const float* bk = (const float*)d_in[4];
    const float* Wv = (const float*)d_in[5];
    const float* bv = (const float*)d_in[6];
    const float* Wo = (const float*)d_in[7];
    const float* bo = (const float*)d_in[8];
    float* out = (float*)d_out;

    const int M = BATCH * SEQ;  // 4096
    char* ws = (char*)d_ws;
    ushort* Xhi    = (ushort*)(ws);
    ushort* Xlo    = (ushort*)(ws + (8u  << 20));
    ushort* CtxHi  = Xhi;                    // X planes dead after QKV gemm
    ushort* CtxLo  = Xlo;
    ushort* QKVb   = (ushort*)(ws + (16u << 20));
    ushort* WqkvHi = (ushort*)(ws + (28u << 20));
    ushort* WqkvLo = (ushort*)(ws + (31u << 20));
    ushort* WotHi  = (ushort*)(ws + (34u << 20));
    ushort* WotLo  = (ushort*)(ws + (36u << 20));
    ushort* Vtb    = (ushort*)(ws + (38u << 20));

    split_x<<<dim3(M * HIDDEN / 4 / 256), 256, 0, stream>>>(X, Xhi, Xlo);
    wtrans_split<<<dim3(16, 16), 256, 0, stream>>>(Wq, WqkvHi, WqkvLo, 0,    1024, HIDDEN);
    wtrans_split<<<dim3(4, 16),  256, 0, stream>>>(Wk, WqkvHi, WqkvLo, 1024, 256,  HIDDEN);
    wtrans_split<<<dim3(4, 16),  256, 0, stream>>>(Wv, WqkvHi, WqkvLo, 1280, 256,  HIDDEN);
    wtrans_split<<<dim3(16, 16), 256, 0, stream>>>(Wo, WotHi,  WotLo,  0,    1024, HIDDEN);

    gemm_split<0><<<dim3(NQKV / 128, M / 128), 256, 0, stream>>>(
        Xhi, Xlo, WqkvHi, WqkvLo, bq, bk, bv, (void*)QKVb, M, NQKV, HIDDEN);

    vtrans_bf<<<dim3(SEQ / 64, NKV, BATCH), 256, 0, stream>>>(QKVb, Vtb);

    attn_mfma2<<<dim3(SEQ / 32, NHEAD, BATCH), 256, 0, stream>>>(QKVb, Vtb, CtxHi, CtxLo);

    gemm_split<1><<<dim3(HIDDEN / 128, M / 128), 256, 0, stream>>>(
        CtxHi, CtxLo, WotHi, WotLo, bo, nullptr, nullptr, (void*)out, M, HIDDEN, HIDDEN);
}

// Round 5
// 277.595 us; speedup vs baseline: 1.2215x; 1.2215x over previous
//
#include <hip/hip_runtime.h>
#include <hip/hip_bf16.h>

#define HIDDEN 1024
#define NHEAD 16
#define NKV 4
#define HDIM 64
#define KVDIM 256
#define SEQ 2048
#define BATCH 2
#define NQKV 1536   // 1024 (Q) + 256 (K) + 256 (V)

typedef __attribute__((ext_vector_type(4)))  float f32x4;
typedef __attribute__((ext_vector_type(16))) float f32x16;
typedef __attribute__((ext_vector_type(8)))  short s16x8;

#if defined(__has_builtin)
#if __has_builtin(__builtin_amdgcn_exp2f)
#define EXP2F(x) __builtin_amdgcn_exp2f(x)
#else
#define EXP2F(x) exp2f(x)
#endif
#else
#define EXP2F(x) exp2f(x)
#endif

static __device__ __forceinline__ ushort f2bf(float f) {
    union { __hip_bfloat16 b; ushort u; } cv; cv.b = __float2bfloat16(f); return cv.u;
}
static __device__ __forceinline__ float bfu2f(ushort u) {
    union { float f; unsigned int i; } cv; cv.i = ((unsigned int)u) << 16; return cv.f;
}
static __device__ __forceinline__ void split2(float v, ushort& h, ushort& l) {
    h = f2bf(v); l = f2bf(v - bfu2f(h));
}
// round-half-up f32->bf16 (positive, finite inputs only — P values)
static __device__ __forceinline__ ushort f2bf_rh(float f) {
    union { float f; unsigned u; } c; c.f = f;
    return (ushort)((c.u + 0x8000u) >> 16);
}
// async global->LDS, 16B per lane. LDS dest = wave-uniform base + lane*16.
static __device__ __forceinline__ void async16(const void* g, void* l) {
    __builtin_amdgcn_global_load_lds((__attribute__((address_space(1))) void*)g,
                                     (__attribute__((address_space(3))) void*)l, 16, 0, 0);
}

// ---------------------------------------------------------------------------
// X fp32 -> hi/lo bf16 planes (elementwise).
// ---------------------------------------------------------------------------
__global__ __launch_bounds__(256)
void split_x(const float* __restrict__ in, ushort* __restrict__ hi,
             ushort* __restrict__ lo)
{
    int i = blockIdx.x * 256 + threadIdx.x;
    float4 v = ((const float4*)in)[i];
    ushort4 h, l;
    split2(v.x, h.x, l.x); split2(v.y, h.y, l.y);
    split2(v.z, h.z, l.z); split2(v.w, h.w, l.w);
    ((ushort4*)hi)[i] = h;
    ((ushort4*)lo)[i] = l;
}

// ---------------------------------------------------------------------------
// W [K][N] fp32 -> transposed split planes T{hi,lo}[roff+n][k] bf16.
// ---------------------------------------------------------------------------
__global__ __launch_bounds__(256)
void wtrans_split(const float* __restrict__ W, ushort* __restrict__ Thi,
                  ushort* __restrict__ Tlo, int roff, int N, int K)
{
    __shared__ float T[64][65];
    const int n0 = blockIdx.x * 64, k0 = blockIdx.y * 64;
    const int tid = threadIdx.x;
#pragma unroll
    for (int it = 0; it < 4; it++) {
        int idx = tid + it * 256;
        int kk = idx >> 4, n4 = (idx & 15) * 4;
        float4 v = *(const float4*)(W + (size_t)(k0 + kk) * N + n0 + n4);
        T[kk][n4 + 0] = v.x; T[kk][n4 + 1] = v.y;
        T[kk][n4 + 2] = v.z; T[kk][n4 + 3] = v.w;
    }
    __syncthreads();
#pragma unroll
    for (int it = 0; it < 4; it++) {
        int idx = tid + it * 256;
        int n = idx >> 4, k4 = (idx & 15) * 4;
        ushort4 h4, l4;
        split2(T[k4 + 0][n], h4.x, l4.x);
        split2(T[k4 + 1][n], h4.y, l4.y);
        split2(T[k4 + 2][n], h4.z, l4.z);
        split2(T[k4 + 3][n], h4.w, l4.w);
        *(ushort4*)(Thi + (size_t)(roff + n0 + n) * K + k0 + k4) = h4;
        *(ushort4*)(Tlo + (size_t)(roff + n0 + n) * K + k0 + k4) = l4;
    }
}

// ---------------------------------------------------------------------------
// Split-bf16 MFMA GEMM (unchanged structure from round 3).
// MODE 0: bf16 out (QKV; Q cols scaled 0.125*log2e for exp2-domain softmax)
// MODE 1: fp32 out
// ---------------------------------------------------------------------------
template <int MODE>
__global__ __launch_bounds__(256)
void gemm_split(const ushort* __restrict__ Ahi, const ushort* __restrict__ Alo,
                const ushort* __restrict__ Bhi, const ushort* __restrict__ Blo,
                const float* __restrict__ b0, const float* __restrict__ b1,
                const float* __restrict__ b2, void* __restrict__ Cout,
                int M, int N, int K)
{
    __shared__ __align__(16) ushort Ah[128 * 32];
    __shared__ __align__(16) ushort Al[128 * 32];
    __shared__ __align__(16) ushort Bh[128 * 32];
    __shared__ __align__(16) ushort Bl[128 * 32];

    const int tid = threadIdx.x;
    const int lane = tid & 63, wv = tid >> 6;
    const int wr = wv >> 1, wc = wv & 1;
    const int m = lane & 15, c = lane >> 4;
    const int row0 = blockIdx.y * 128, col0 = blockIdx.x * 128;

    const ushort* gA0[2]; const ushort* gA1[2];
    const ushort* gB0[2]; const ushort* gB1[2];
    int ldsOff[2];
#pragma unroll
    for (int it = 0; it < 2; it++) {
        int idx = it * 256 + tid;
        int r = idx >> 2, cb = (idx & 3) * 8;
        gA0[it] = Ahi + (size_t)(row0 + r) * K + cb;
        gA1[it] = Alo + (size_t)(row0 + r) * K + cb;
        gB0[it] = Bhi + (size_t)(col0 + r) * K + cb;
        gB1[it] = Blo + (size_t)(col0 + r) * K + cb;
        ldsOff[it] = (it * 256 + wv * 64) * 8;
    }

    f32x4 acc[4][4];
#pragma unroll
    for (int t = 0; t < 4; t++)
#pragma unroll
        for (int u = 0; u < 4; u++) acc[t][u] = (f32x4){0.f, 0.f, 0.f, 0.f};

    for (int k0 = 0; k0 < K; k0 += 32) {
        __syncthreads();
#pragma unroll
        for (int it = 0; it < 2; it++) {
            async16(gA0[it] + k0, Ah + ldsOff[it]);
            async16(gA1[it] + k0, Al + ldsOff[it]);
            async16(gB0[it] + k0, Bh + ldsOff[it]);
            async16(gB1[it] + k0, Bl + ldsOff[it]);
        }
        __syncthreads();

        s16x8 ah[4], al[4], bh[4], bl[4];
#pragma unroll
        for (int t = 0; t < 4; t++) {
            int ra = (64 * wr + 16 * t + m) * 32 + c * 8;
            int rb = (64 * wc + 16 * t + m) * 32 + c * 8;
            ah[t] = *(const s16x8*)&Ah[ra];
            al[t] = *(const s16x8*)&Al[ra];
            bh[t] = *(const s16x8*)&Bh[rb];
            bl[t] = *(const s16x8*)&Bl[rb];
        }
#pragma unroll
        for (int t = 0; t < 4; t++)
#pragma unroll
            for (int u = 0; u < 4; u++) {
                acc[t][u] = __builtin_amdgcn_mfma_f32_16x16x32_bf16(ah[t], bh[u], acc[t][u], 0, 0, 0);
                acc[t][u] = __builtin_amdgcn_mfma_f32_16x16x32_bf16(ah[t], bl[u], acc[t][u], 0, 0, 0);
                acc[t][u] = __builtin_amdgcn_mfma_f32_16x16x32_bf16(al[t], bh[u], acc[t][u], 0, 0, 0);
            }
    }

    const int orow = row0 + 64 * wr + 4 * c;
    const int ocol = col0 + 64 * wc + m;
    if (MODE == 0) {
        ushort* Cb = (ushort*)Cout;
#pragma unroll
        for (int u = 0; u < 4; u++) {
            int n = ocol + 16 * u;
            float bias, scl;
            if (n < 1024)      { bias = b0[n];        scl = 0.18033688f; }  // 0.125*log2(e)
            else if (n < 1280) { bias = b1[n - 1024]; scl = 1.0f; }
            else               { bias = b2[n - 1280]; scl = 1.0f; }
#pragma unroll
            for (int t = 0; t < 4; t++)
#pragma unroll
                for (int r = 0; r < 4; r++)
                    Cb[(size_t)(orow + 16 * t + r) * N + n] = f2bf((acc[t][u][r] + bias) * scl);
        }
    } else {
        float* Cf = (float*)Cout;
#pragma unroll
        for (int u = 0; u < 4; u++) {
            int n = ocol + 16 * u;
            float bias = b0[n];
#pragma unroll
            for (int t = 0; t < 4; t++)
#pragma unroll
                for (int r = 0; r < 4; r++)
                    Cf[(size_t)(orow + 16 * t + r) * N + n] = acc[t][u][r] + bias;
        }
    }
}

// ---------------------------------------------------------------------------
// Pack K and V (bf16 cols of QKV) into fragment-major buffers so the
// attention wave loads are lane-contiguous (base + lane*16):
//  Kf[((b*4+hk)*64 + t32)*4 + kc][lane][8]:
//     elem = K[key = t32*32 + (lane&31)][hk*64 + kc*16 + (lane>>5)*8 + j]
//  Vf[(((b*4+hk)*32 + kt)*8 + kc*2 + dn)][lane][8]:
//     elem = V[key = kt*64 + kc*16 + (lane>>5)*8 + j][hk*64 + dn*32 + (lane&31)]
// Block = one (kt64, hk, b) tile.
// ---------------------------------------------------------------------------
__global__ __launch_bounds__(256)
void kvpack(const ushort* __restrict__ QKV, ushort* __restrict__ Kf,
            ushort* __restrict__ Vf)
{
    __shared__ __align__(16) ushort Kt[64][72];
    __shared__ __align__(16) ushort Vt[64][72];
    const int kt = blockIdx.x, hk = blockIdx.y, b = blockIdx.z;
    const int tid = threadIdx.x;

#pragma unroll
    for (int it = 0; it < 2; it++) {
        int idx = tid + it * 256;
        int r = idx >> 3, c8 = (idx & 7) * 8;
        const ushort* src = QKV + (size_t)(b * SEQ + kt * 64 + r) * NQKV + hk * HDIM + c8;
        *(s16x8*)&Kt[r][c8] = *(const s16x8*)(src + 1024);
        *(s16x8*)&Vt[r][c8] = *(const s16x8*)(src + 1280);
    }
    __syncthreads();

    // K fragments
#pragma unroll
    for (int it = 0; it < 2; it++) {
        int idx = tid + it * 256;            // [0,512)
        int t32 = idx >> 8, kc = (idx >> 6) & 3, lane = idx & 63;
        int n32 = lane & 31, h5 = lane >> 5;
        s16x8 fr = *(const s16x8*)&Kt[t32 * 32 + n32][kc * 16 + h5 * 8];
        size_t flat = ((size_t)(((b * NKV + hk) * 64 + kt * 2 + t32) * 4 + kc) * 64 + lane) * 8;
        *(s16x8*)(Kf + flat) = fr;
    }
    // V fragments (column walk in LDS)
#pragma unroll
    for (int it = 0; it < 2; it++) {
        int idx = tid + it * 256;
        int kcdn = idx >> 6, lane = idx & 63;
        int kc = kcdn >> 1, dn = kcdn & 1;
        int n32 = lane & 31, h5 = lane >> 5;
        s16x8 fr;
#pragma unroll
        for (int j = 0; j < 8; j++)
            fr[j] = (short)Vt[kc * 16 + h5 * 8 + j][dn * 32 + n32];
        size_t flat = ((size_t)(((b * NKV + hk) * 32 + kt) * 8 + kc * 2 + dn) * 64 + lane) * 8;
        *(s16x8*)(Vf + flat) = fr;
    }
}

// ---------------------------------------------------------------------------
// Flash attention v3: 32x32x16 MFMA, 512 thr = 2 q-groups x 4 kt-split waves,
// zero in-loop barriers, fragment-major coalesced K/V loads from Kf/Vf.
// No-max softmax in exp2 domain (log2e folded into Q). l via ones-column MFMA.
// End: two-phase merge of per-wave partials through LDS (unioned with Ps).
// C/D layout (verified m74/m101): col=lane&31, row=(reg&3)+8*(reg>>2)+4*(lane>>5).
// ---------------------------------------------------------------------------
__global__ __launch_bounds__(512)
void attn_mfma3(const ushort* __restrict__ QKV, const ushort* __restrict__ Kf,
                const ushort* __restrict__ Vf,
                ushort* __restrict__ Chi, ushort* __restrict__ Clo)
{
    __shared__ __align__(16) ushort Ps[8][32][72];   // 36,864 B; merge bufs alias
    float* OLb = (float*)&Ps[0][0][0];               // [4][32][64] = 32,768 B
    float* LLb = (float*)((char*)&Ps[0][0][0] + 33024);  // [4][32]

    const int tid = threadIdx.x, w = tid >> 6, lane = tid & 63;
    const int g = w >> 2, ws_ = w & 3;               // q-group, kt-split index
    const int n32 = lane & 31, h5 = lane >> 5;
    const int h = blockIdx.y, b = blockIdx.z, hk = h >> 2;
    const int q0 = blockIdx.x * 64 + g * 32;

    // Q A-fragments (4 k-chunks of 16), hoisted
    const ushort* qrow = QKV + (size_t)(b * SEQ + q0 + n32) * NQKV + h * HDIM + h5 * 8;
    s16x8 aq[4];
#pragma unroll
    for (int kc = 0; kc < 4; kc++) aq[kc] = *(const s16x8*)(qrow + kc * 16);

    f32x16 accO[2], accl;
#pragma unroll
    for (int j = 0; j < 16; j++) { accO[0][j] = 0.f; accO[1][j] = 0.f; accl[j] = 0.f; }

    s16x8 ones;
#pragma unroll
    for (int j = 0; j < 8; j++) ones[j] = (short)0x3F80;   // bf16 1.0

    const ushort* kfb = Kf + ((size_t)(b * NKV + hk) * 256 + (size_t)lane) * 8
                           - (size_t)0;   // base; tile offset added per use
    const ushort* vfb = Vf + ((size_t)(b * NKV + hk) * 256 + (size_t)lane) * 8;
    // Kf stride between (t32,kc) slots: 64*8 elems; region per (b,hk): 64*4 slots
    // Vf stride: same 512; region per (b,hk): 32*8 slots.
    // Recompute clean bases:
    const ushort* kf0 = Kf + (size_t)(b * NKV + hk) * (64 * 4 * 64 * 8) + (size_t)lane * 8;
    const ushort* vf0 = Vf + (size_t)(b * NKV + hk) * (32 * 8 * 64 * 8) + (size_t)lane * 8;
    (void)kfb; (void)vfb;

    for (int kt = ws_; kt < SEQ / 64; kt += 4) {
        // --- scores per 32-key tile, exp2, pack to Ps ---
#pragma unroll
        for (int kn = 0; kn < 2; kn++) {
            f32x16 S;
#pragma unroll
            for (int j = 0; j < 16; j++) S[j] = 0.f;
#pragma unroll
            for (int kc = 0; kc < 4; kc++) {
                s16x8 kf = *(const s16x8*)(kf0 + (size_t)((kt * 2 + kn) * 4 + kc) * 512);
                S = __builtin_amdgcn_mfma_f32_32x32x16_bf16(aq[kc], kf, S, 0, 0, 0);
            }
#pragma unroll
            for (int reg = 0; reg < 16; reg++) {
                int q = (reg & 3) + 8 * (reg >> 2) + 4 * h5;
                Ps[w][q][kn * 32 + n32] = f2bf_rh(EXP2F(S[reg]));
            }
        }

        // --- P A-fragments (same-wave LDS RAW; DS pipe in-order) ---
        s16x8 pa[4];
#pragma unroll
        for (int kc = 0; kc < 4; kc++)
            pa[kc] = *(const s16x8*)&Ps[w][n32][kc * 16 + h5 * 8];

        // --- O += P V ; l += P * 1 ---
#pragma unroll
        for (int kc = 0; kc < 4; kc++) {
            accl = __builtin_amdgcn_mfma_f32_32x32x16_bf16(pa[kc], ones, accl, 0, 0, 0);
#pragma unroll
            for (int dn = 0; dn < 2; dn++) {
                s16x8 vf = *(const s16x8*)(vf0 + (size_t)(kt * 8 + kc * 2 + dn) * 512);
                accO[dn] = __builtin_amdgcn_mfma_f32_32x32x16_bf16(pa[kc], vf, accO[dn], 0, 0, 0);
            }
        }
    }

    __syncthreads();   // everyone done with Ps — safe to alias merge buffers

    const int qq = tid >> 4;          // 0..31
    const int d0 = (tid & 15) * 4;    // 0..60
#pragma unroll
    for (int phase = 0; phase < 2; phase++) {
        if (g == phase) {
#pragma unroll
            for (int reg = 0; reg < 16; reg++) {
                int q = (reg & 3) + 8 * (reg >> 2) + 4 * h5;
                OLb[(ws_ * 32 + q) * 64 + n32]      = accO[0][reg];
                OLb[(ws_ * 32 + q) * 64 + 32 + n32] = accO[1][reg];
                if (n32 == 0) LLb[ws_ * 32 + q] = accl[reg];
            }
        }
        __syncthreads();
        {
            float lsum = LLb[qq] + LLb[32 + qq] + LLb[64 + qq] + LLb[96 + qq];
            float inv = 1.f / lsum;
            float o[4];
#pragma unroll
            for (int e = 0; e < 4; e++)
                o[e] = (OLb[(0 * 32 + qq) * 64 + d0 + e] + OLb[(1 * 32 + qq) * 64 + d0 + e] +
                        OLb[(2 * 32 + qq) * 64 + d0 + e] + OLb[(3 * 32 + qq) * 64 + d0 + e]) * inv;
            ushort4 hs, ls;
            split2(o[0], hs.x, ls.x); split2(o[1], hs.y, ls.y);
            split2(o[2], hs.z, ls.z); split2(o[3], hs.w, ls.w);
            size_t off = (size_t)(b * SEQ + blockIdx.x * 64 + phase * 32 + qq) * HIDDEN
                       + h * HDIM + d0;
            *(ushort4*)(Chi + off) = hs;
            *(ushort4*)(Clo + off) = ls;
        }
        __syncthreads();   // before next phase overwrites merge buffers
    }
}

// ---------------------------------------------------------------------------
extern "C" void kernel_launch(void* const* d_in, const int* in_sizes, int n_in,
                              void* d_out, int out_size, void* d_ws, size_t ws_size,
                              hipStream_t stream)
{
    const float* X  = (const float*)d_in[0];
    const float* Wq = (const float*)d_in[1];
    const float* bq = (const float*)d_in[2];
    const float* Wk = (const float*)d_in[3];
    const float* bk = (const float*)d_in[4];
    const float* Wv = (const float*)d_in[5];
    const float* bv = (const float*)d_in[6];
    const float* Wo = (const float*)d_in[7];
    const float* bo = (const float*)d_in[8];
    float* out = (float*)d_out;

    const int M = BATCH * SEQ;  // 4096
    // ws layout (40 MB): Xhi/CtxHi 8 | Xlo/CtxLo 8 | QKVb 12 | WqkvHi 3 | WqkvLo 3
    // | Kf 2 (aliases WotHi: Wo transpose runs AFTER attention) | WotLo 2 | Vf 2
    char* ws = (char*)d_ws;
    ushort* Xhi    = (ushort*)(ws);
    ushort* Xlo    = (ushort*)(ws + (8u  << 20));
    ushort* CtxHi  = Xhi;
    ushort* CtxLo  = Xlo;
    ushort* QKVb   = (ushort*)(ws + (16u << 20));
    ushort* WqkvHi = (ushort*)(ws + (28u << 20));
    ushort* WqkvLo = (ushort*)(ws + (31u << 20));
    ushort* Kf     = (ushort*)(ws + (34u << 20));   // lives until attention ends
    ushort* WotHi  = (ushort*)(ws + (34u << 20));   // written after attention
    ushort* WotLo  = (ushort*)(ws + (36u << 20));
    ushort* Vf     = (ushort*)(ws + (38u << 20));

    split_x<<<dim3(M * HIDDEN / 4 / 256), 256, 0, stream>>>(X, Xhi, Xlo);
    wtrans_split<<<dim3(16, 16), 256, 0, stream>>>(Wq, WqkvHi, WqkvLo, 0,    1024, HIDDEN);
    wtrans_split<<<dim3(4, 16),  256, 0, stream>>>(Wk, WqkvHi, WqkvLo, 1024, 256,  HIDDEN);
    wtrans_split<<<dim3(4, 16),  256, 0, stream>>>(Wv, WqkvHi, WqkvLo, 1280, 256,  HIDDEN);

    gemm_split<0><<<dim3(NQKV / 128, M / 128), 256, 0, stream>>>(
        Xhi, Xlo, WqkvHi, WqkvLo, bq, bk, bv, (void*)QKVb, M, NQKV, HIDDEN);

    kvpack<<<dim3(SEQ / 64, NKV, BATCH), 256, 0, stream>>>(QKVb, Kf, Vf);

    attn_mfma3<<<dim3(SEQ / 64, NHEAD, BATCH), 512, 0, stream>>>(QKVb, Kf, Vf, CtxHi, CtxLo);

    // Wo transpose AFTER attention (WotHi aliases Kf)
    wtrans_split<<<dim3(16, 16), 256, 0, stream>>>(Wo, WotHi, WotLo, 0, 1024, HIDDEN);

    gemm_split<1><<<dim3(HIDDEN / 128, M / 128), 256, 0, stream>>>(
        CtxHi, CtxLo, WotHi, WotLo, bo, nullptr, nullptr, (void*)out, M, HIDDEN, HIDDEN);
}

// Round 6
// 261.669 us; speedup vs baseline: 1.2959x; 1.0609x over previous
//
#include <hip/hip_runtime.h>
#include <hip/hip_bf16.h>

#define HIDDEN 1024
#define NHEAD 16
#define NKV 4
#define HDIM 64
#define KVDIM 256
#define SEQ 2048
#define BATCH 2
#define NQKV 1536   // 1024 (Q) + 256 (K) + 256 (V)

typedef __attribute__((ext_vector_type(4)))  float f32x4;
typedef __attribute__((ext_vector_type(16))) float f32x16;
typedef __attribute__((ext_vector_type(8)))  short s16x8;

#if defined(__has_builtin)
#if __has_builtin(__builtin_amdgcn_exp2f)
#define EXP2F(x) __builtin_amdgcn_exp2f(x)
#else
#define EXP2F(x) exp2f(x)
#endif
#else
#define EXP2F(x) exp2f(x)
#endif

static __device__ __forceinline__ ushort f2bf(float f) {
    union { __hip_bfloat16 b; ushort u; } cv; cv.b = __float2bfloat16(f); return cv.u;
}
static __device__ __forceinline__ float bfu2f(ushort u) {
    union { float f; unsigned int i; } cv; cv.i = ((unsigned int)u) << 16; return cv.f;
}
static __device__ __forceinline__ void split2(float v, ushort& h, ushort& l) {
    h = f2bf(v); l = f2bf(v - bfu2f(h));
}
// round-half-up f32->bf16 (positive, finite inputs only — P values)
static __device__ __forceinline__ ushort f2bf_rh(float f) {
    union { float f; unsigned u; } c; c.f = f;
    return (ushort)((c.u + 0x8000u) >> 16);
}
// async global->LDS, 16B per lane. LDS dest = wave-uniform base + lane*16.
static __device__ __forceinline__ void async16(const void* g, void* l) {
    __builtin_amdgcn_global_load_lds((__attribute__((address_space(1))) void*)g,
                                     (__attribute__((address_space(3))) void*)l, 16, 0, 0);
}

// ---------------------------------------------------------------------------
// X fp32 -> hi/lo bf16 planes (elementwise).
// ---------------------------------------------------------------------------
__global__ __launch_bounds__(256)
void split_x(const float* __restrict__ in, ushort* __restrict__ hi,
             ushort* __restrict__ lo)
{
    int i = blockIdx.x * 256 + threadIdx.x;
    float4 v = ((const float4*)in)[i];
    ushort4 h, l;
    split2(v.x, h.x, l.x); split2(v.y, h.y, l.y);
    split2(v.z, h.z, l.z); split2(v.w, h.w, l.w);
    ((ushort4*)hi)[i] = h;
    ((ushort4*)lo)[i] = l;
}

// ---------------------------------------------------------------------------
// W [K][N] fp32 -> transposed split planes T{hi,lo}[roff+n][k] bf16.
// ---------------------------------------------------------------------------
__global__ __launch_bounds__(256)
void wtrans_split(const float* __restrict__ W, ushort* __restrict__ Thi,
                  ushort* __restrict__ Tlo, int roff, int N, int K)
{
    __shared__ float T[64][65];
    const int n0 = blockIdx.x * 64, k0 = blockIdx.y * 64;
    const int tid = threadIdx.x;
#pragma unroll
    for (int it = 0; it < 4; it++) {
        int idx = tid + it * 256;
        int kk = idx >> 4, n4 = (idx & 15) * 4;
        float4 v = *(const float4*)(W + (size_t)(k0 + kk) * N + n0 + n4);
        T[kk][n4 + 0] = v.x; T[kk][n4 + 1] = v.y;
        T[kk][n4 + 2] = v.z; T[kk][n4 + 3] = v.w;
    }
    __syncthreads();
#pragma unroll
    for (int it = 0; it < 4; it++) {
        int idx = tid + it * 256;
        int n = idx >> 4, k4 = (idx & 15) * 4;
        ushort4 h4, l4;
        split2(T[k4 + 0][n], h4.x, l4.x);
        split2(T[k4 + 1][n], h4.y, l4.y);
        split2(T[k4 + 2][n], h4.z, l4.z);
        split2(T[k4 + 3][n], h4.w, l4.w);
        *(ushort4*)(Thi + (size_t)(roff + n0 + n) * K + k0 + k4) = h4;
        *(ushort4*)(Tlo + (size_t)(roff + n0 + n) * K + k0 + k4) = l4;
    }
}

// ---------------------------------------------------------------------------
// Split-bf16 MFMA GEMM (unchanged from round 3).
// MODE 0: bf16 out (QKV; Q cols scaled 0.125*log2e for exp2-domain softmax)
// MODE 1: fp32 out
// ---------------------------------------------------------------------------
template <int MODE>
__global__ __launch_bounds__(256)
void gemm_split(const ushort* __restrict__ Ahi, const ushort* __restrict__ Alo,
                const ushort* __restrict__ Bhi, const ushort* __restrict__ Blo,
                const float* __restrict__ b0, const float* __restrict__ b1,
                const float* __restrict__ b2, void* __restrict__ Cout,
                int M, int N, int K)
{
    __shared__ __align__(16) ushort Ah[128 * 32];
    __shared__ __align__(16) ushort Al[128 * 32];
    __shared__ __align__(16) ushort Bh[128 * 32];
    __shared__ __align__(16) ushort Bl[128 * 32];

    const int tid = threadIdx.x;
    const int lane = tid & 63, wv = tid >> 6;
    const int wr = wv >> 1, wc = wv & 1;
    const int m = lane & 15, c = lane >> 4;
    const int row0 = blockIdx.y * 128, col0 = blockIdx.x * 128;

    const ushort* gA0[2]; const ushort* gA1[2];
    const ushort* gB0[2]; const ushort* gB1[2];
    int ldsOff[2];
#pragma unroll
    for (int it = 0; it < 2; it++) {
        int idx = it * 256 + tid;
        int r = idx >> 2, cb = (idx & 3) * 8;
        gA0[it] = Ahi + (size_t)(row0 + r) * K + cb;
        gA1[it] = Alo + (size_t)(row0 + r) * K + cb;
        gB0[it] = Bhi + (size_t)(col0 + r) * K + cb;
        gB1[it] = Blo + (size_t)(col0 + r) * K + cb;
        ldsOff[it] = (it * 256 + wv * 64) * 8;
    }

    f32x4 acc[4][4];
#pragma unroll
    for (int t = 0; t < 4; t++)
#pragma unroll
        for (int u = 0; u < 4; u++) acc[t][u] = (f32x4){0.f, 0.f, 0.f, 0.f};

    for (int k0 = 0; k0 < K; k0 += 32) {
        __syncthreads();
#pragma unroll
        for (int it = 0; it < 2; it++) {
            async16(gA0[it] + k0, Ah + ldsOff[it]);
            async16(gA1[it] + k0, Al + ldsOff[it]);
            async16(gB0[it] + k0, Bh + ldsOff[it]);
            async16(gB1[it] + k0, Bl + ldsOff[it]);
        }
        __syncthreads();

        s16x8 ah[4], al[4], bh[4], bl[4];
#pragma unroll
        for (int t = 0; t < 4; t++) {
            int ra = (64 * wr + 16 * t + m) * 32 + c * 8;
            int rb = (64 * wc + 16 * t + m) * 32 + c * 8;
            ah[t] = *(const s16x8*)&Ah[ra];
            al[t] = *(const s16x8*)&Al[ra];
            bh[t] = *(const s16x8*)&Bh[rb];
            bl[t] = *(const s16x8*)&Bl[rb];
        }
#pragma unroll
        for (int t = 0; t < 4; t++)
#pragma unroll
            for (int u = 0; u < 4; u++) {
                acc[t][u] = __builtin_amdgcn_mfma_f32_16x16x32_bf16(ah[t], bh[u], acc[t][u], 0, 0, 0);
                acc[t][u] = __builtin_amdgcn_mfma_f32_16x16x32_bf16(ah[t], bl[u], acc[t][u], 0, 0, 0);
                acc[t][u] = __builtin_amdgcn_mfma_f32_16x16x32_bf16(al[t], bh[u], acc[t][u], 0, 0, 0);
            }
    }

    const int orow = row0 + 64 * wr + 4 * c;
    const int ocol = col0 + 64 * wc + m;
    if (MODE == 0) {
        ushort* Cb = (ushort*)Cout;
#pragma unroll
        for (int u = 0; u < 4; u++) {
            int n = ocol + 16 * u;
            float bias, scl;
            if (n < 1024)      { bias = b0[n];        scl = 0.18033688f; }  // 0.125*log2(e)
            else if (n < 1280) { bias = b1[n - 1024]; scl = 1.0f; }
            else               { bias = b2[n - 1280]; scl = 1.0f; }
#pragma unroll
            for (int t = 0; t < 4; t++)
#pragma unroll
                for (int r = 0; r < 4; r++)
                    Cb[(size_t)(orow + 16 * t + r) * N + n] = f2bf((acc[t][u][r] + bias) * scl);
        }
    } else {
        float* Cf = (float*)Cout;
#pragma unroll
        for (int u = 0; u < 4; u++) {
            int n = ocol + 16 * u;
            float bias = b0[n];
#pragma unroll
            for (int t = 0; t < 4; t++)
#pragma unroll
                for (int r = 0; r < 4; r++)
                    Cf[(size_t)(orow + 16 * t + r) * N + n] = acc[t][u][r] + bias;
        }
    }
}

// ---------------------------------------------------------------------------
// Pack K and V (bf16 cols of QKV) into fragment-major buffers (unchanged).
// ---------------------------------------------------------------------------
__global__ __launch_bounds__(256)
void kvpack(const ushort* __restrict__ QKV, ushort* __restrict__ Kf,
            ushort* __restrict__ Vf)
{
    __shared__ __align__(16) ushort Kt[64][72];
    __shared__ __align__(16) ushort Vt[64][72];
    const int kt = blockIdx.x, hk = blockIdx.y, b = blockIdx.z;
    const int tid = threadIdx.x;

#pragma unroll
    for (int it = 0; it < 2; it++) {
        int idx = tid + it * 256;
        int r = idx >> 3, c8 = (idx & 7) * 8;
        const ushort* src = QKV + (size_t)(b * SEQ + kt * 64 + r) * NQKV + hk * HDIM + c8;
        *(s16x8*)&Kt[r][c8] = *(const s16x8*)(src + 1024);
        *(s16x8*)&Vt[r][c8] = *(const s16x8*)(src + 1280);
    }
    __syncthreads();

#pragma unroll
    for (int it = 0; it < 2; it++) {
        int idx = tid + it * 256;
        int t32 = idx >> 8, kc = (idx >> 6) & 3, lane = idx & 63;
        int n32 = lane & 31, h5 = lane >> 5;
        s16x8 fr = *(const s16x8*)&Kt[t32 * 32 + n32][kc * 16 + h5 * 8];
        size_t flat = ((size_t)(((b * NKV + hk) * 64 + kt * 2 + t32) * 4 + kc) * 64 + lane) * 8;
        *(s16x8*)(Kf + flat) = fr;
    }
#pragma unroll
    for (int it = 0; it < 2; it++) {
        int idx = tid + it * 256;
        int kcdn = idx >> 6, lane = idx & 63;
        int kc = kcdn >> 1, dn = kcdn & 1;
        int n32 = lane & 31, h5 = lane >> 5;
        s16x8 fr;
#pragma unroll
        for (int j = 0; j < 8; j++)
            fr[j] = (short)Vt[kc * 16 + h5 * 8 + j][dn * 32 + n32];
        size_t flat = ((size_t)(((b * NKV + hk) * 32 + kt) * 8 + kc * 2 + dn) * 64 + lane) * 8;
        *(s16x8*)(Vf + flat) = fr;
    }
}

// ---------------------------------------------------------------------------
// Flash attention v4: round-5 structure + depth-1 software pipeline.
// Per iteration: issue V(prev)+K(cur) loads -> ds_read P(prev) -> PV(prev)
// -> QK(cur) -> exp2 -> write P(cur). Same-buffer WAR is safe: per-wave DS
// ops are in-order and the P(prev) reads precede P(cur) writes in program
// order. V loaded one-iteration-late => no cross-iteration register carry.
// ---------------------------------------------------------------------------
__global__ __launch_bounds__(512, 2)
void attn_mfma4(const ushort* __restrict__ QKV, const ushort* __restrict__ Kf,
                const ushort* __restrict__ Vf,
                ushort* __restrict__ Chi, ushort* __restrict__ Clo)
{
    __shared__ __align__(16) ushort Ps[8][32][72];   // 36,864 B; merge bufs alias
    float* OLb = (float*)&Ps[0][0][0];               // [4][32][64] = 32,768 B
    float* LLb = (float*)((char*)&Ps[0][0][0] + 33024);  // [4][32]

    const int tid = threadIdx.x, w = tid >> 6, lane = tid & 63;
    const int g = w >> 2, ws_ = w & 3;               // q-group, kt-split index
    const int n32 = lane & 31, h5 = lane >> 5;
    const int h = blockIdx.y, b = blockIdx.z, hk = h >> 2;
    const int q0 = blockIdx.x * 64 + g * 32;

    // Q A-fragments (4 k-chunks of 16), hoisted
    const ushort* qrow = QKV + (size_t)(b * SEQ + q0 + n32) * NQKV + h * HDIM + h5 * 8;
    s16x8 aq[4];
#pragma unroll
    for (int kc = 0; kc < 4; kc++) aq[kc] = *(const s16x8*)(qrow + kc * 16);

    f32x16 accO[2], accl;
#pragma unroll
    for (int j = 0; j < 16; j++) { accO[0][j] = 0.f; accO[1][j] = 0.f; accl[j] = 0.f; }

    s16x8 ones;
#pragma unroll
    for (int j = 0; j < 8; j++) ones[j] = (short)0x3F80;   // bf16 1.0

    const ushort* kf0 = Kf + (size_t)(b * NKV + hk) * (64 * 4 * 64 * 8) + (size_t)lane * 8;
    const ushort* vf0 = Vf + (size_t)(b * NKV + hk) * (32 * 8 * 64 * 8) + (size_t)lane * 8;

    s16x8 kreg[8], vreg[8];

#define LOAD_K(kt_) do {                                                      \
    _Pragma("unroll")                                                         \
    for (int kn = 0; kn < 2; kn++)                                            \
        _Pragma("unroll")                                                     \
        for (int kc = 0; kc < 4; kc++)                                        \
            kreg[kn * 4 + kc] =                                               \
                *(const s16x8*)(kf0 + (size_t)(((kt_) * 2 + kn) * 4 + kc) * 512); \
} while (0)

#define LOAD_V(kt_) do {                                                      \
    _Pragma("unroll")                                                         \
    for (int kc = 0; kc < 4; kc++)                                            \
        _Pragma("unroll")                                                     \
        for (int dn = 0; dn < 2; dn++)                                        \
            vreg[kc * 2 + dn] =                                               \
                *(const s16x8*)(vf0 + (size_t)((kt_) * 8 + kc * 2 + dn) * 512); \
} while (0)

#define QK_EXP_STORE() do {                                                   \
    _Pragma("unroll")                                                         \
    for (int kn = 0; kn < 2; kn++) {                                          \
        f32x16 S;                                                             \
        _Pragma("unroll")                                                     \
        for (int j = 0; j < 16; j++) S[j] = 0.f;                              \
        _Pragma("unroll")                                                     \
        for (int kc = 0; kc < 4; kc++)                                        \
            S = __builtin_amdgcn_mfma_f32_32x32x16_bf16(aq[kc],               \
                    kreg[kn * 4 + kc], S, 0, 0, 0);                           \
        _Pragma("unroll")                                                     \
        for (int reg = 0; reg < 16; reg++) {                                  \
            int q = (reg & 3) + 8 * (reg >> 2) + 4 * h5;                      \
            Ps[w][q][kn * 32 + n32] = f2bf_rh(EXP2F(S[reg]));                 \
        }                                                                     \
    }                                                                         \
} while (0)

#define PV_STEP() do {                                                        \
    s16x8 pa[4];                                                              \
    _Pragma("unroll")                                                         \
    for (int kc = 0; kc < 4; kc++)                                            \
        pa[kc] = *(const s16x8*)&Ps[w][n32][kc * 16 + h5 * 8];                \
    _Pragma("unroll")                                                         \
    for (int kc = 0; kc < 4; kc++) {                                          \
        accl = __builtin_amdgcn_mfma_f32_32x32x16_bf16(pa[kc], ones, accl, 0, 0, 0); \
        _Pragma("unroll")                                                     \
        for (int dn = 0; dn < 2; dn++)                                        \
            accO[dn] = __builtin_amdgcn_mfma_f32_32x32x16_bf16(pa[kc],        \
                           vreg[kc * 2 + dn], accO[dn], 0, 0, 0);             \
    }                                                                         \
} while (0)

    // prologue: first tile's scores
    LOAD_K(ws_);
    QK_EXP_STORE();

    for (int i = 1; i < 8; i++) {
        const int ktc = ws_ + 4 * i;
        LOAD_V(ktc - 4);     // V for previous tile (issued first: partial vm wait)
        LOAD_K(ktc);         // K for current tile
        PV_STEP();           // PV(prev): reads Ps BEFORE the writes below (in-order DS)
        QK_EXP_STORE();      // scores(cur) + overwrite Ps
    }

    // epilogue: last tile's PV
    LOAD_V(ws_ + 28);
    PV_STEP();

#undef LOAD_K
#undef LOAD_V
#undef QK_EXP_STORE
#undef PV_STEP

    __syncthreads();   // everyone done with Ps — safe to alias merge buffers

    const int qq = tid >> 4;          // 0..31
    const int d0 = (tid & 15) * 4;    // 0..60
#pragma unroll
    for (int phase = 0; phase < 2; phase++) {
        if (g == phase) {
#pragma unroll
            for (int reg = 0; reg < 16; reg++) {
                int q = (reg & 3) + 8 * (reg >> 2) + 4 * h5;
                OLb[(ws_ * 32 + q) * 64 + n32]      = accO[0][reg];
                OLb[(ws_ * 32 + q) * 64 + 32 + n32] = accO[1][reg];
                if (n32 == 0) LLb[ws_ * 32 + q] = accl[reg];
            }
        }
        __syncthreads();
        {
            float lsum = LLb[qq] + LLb[32 + qq] + LLb[64 + qq] + LLb[96 + qq];
            float inv = 1.f / lsum;
            float o[4];
#pragma unroll
            for (int e = 0; e < 4; e++)
                o[e] = (OLb[(0 * 32 + qq) * 64 + d0 + e] + OLb[(1 * 32 + qq) * 64 + d0 + e] +
                        OLb[(2 * 32 + qq) * 64 + d0 + e] + OLb[(3 * 32 + qq) * 64 + d0 + e]) * inv;
            ushort4 hs, ls;
            split2(o[0], hs.x, ls.x); split2(o[1], hs.y, ls.y);
            split2(o[2], hs.z, ls.z); split2(o[3], hs.w, ls.w);
            size_t off = (size_t)(b * SEQ + blockIdx.x * 64 + phase * 32 + qq) * HIDDEN
                       + h * HDIM + d0;
            *(ushort4*)(Chi + off) = hs;
            *(ushort4*)(Clo + off) = ls;
        }
        __syncthreads();   // before next phase overwrites merge buffers
    }
}

// ---------------------------------------------------------------------------
extern "C" void kernel_launch(void* const* d_in, const int* in_sizes, int n_in,
                              void* d_out, int out_size, void* d_ws, size_t ws_size,
                              hipStream_t stream)
{
    const float* X  = (const float*)d_in[0];
    const float* Wq = (const float*)d_in[1];
    const float* bq = (const float*)d_in[2];
    const float* Wk = (const float*)d_in[3];
    const float* bk = (const float*)d_in[4];
    const float* Wv = (const float*)d_in[5];
    const float* bv = (const float*)d_in[6];
    const float* Wo = (const float*)d_in[7];
    const float* bo = (const float*)d_in[8];
    float* out = (float*)d_out;

    const int M = BATCH * SEQ;  // 4096
    // ws layout (40 MB): Xhi/CtxHi 8 | Xlo/CtxLo 8 | QKVb 12 | WqkvHi 3 | WqkvLo 3
    // | Kf 2 (aliases WotHi: Wo transpose runs AFTER attention) | WotLo 2 | Vf 2
    char* ws = (char*)d_ws;
    ushort* Xhi    = (ushort*)(ws);
    ushort* Xlo    = (ushort*)(ws + (8u  << 20));
    ushort* CtxHi  = Xhi;
    ushort* CtxLo  = Xlo;
    ushort* QKVb   = (ushort*)(ws + (16u << 20));
    ushort* WqkvHi = (ushort*)(ws + (28u << 20));
    ushort* WqkvLo = (ushort*)(ws + (31u << 20));
    ushort* Kf     = (ushort*)(ws + (34u << 20));   // lives until attention ends
    ushort* WotHi  = (ushort*)(ws + (34u << 20));   // written after attention
    ushort* WotLo  = (ushort*)(ws + (36u << 20));
    ushort* Vf     = (ushort*)(ws + (38u << 20));

    split_x<<<dim3(M * HIDDEN / 4 / 256), 256, 0, stream>>>(X, Xhi, Xlo);
    wtrans_split<<<dim3(16, 16), 256, 0, stream>>>(Wq, WqkvHi, WqkvLo, 0,    1024, HIDDEN);
    wtrans_split<<<dim3(4, 16),  256, 0, stream>>>(Wk, WqkvHi, WqkvLo, 1024, 256,  HIDDEN);
    wtrans_split<<<dim3(4, 16),  256, 0, stream>>>(Wv, WqkvHi, WqkvLo, 1280, 256,  HIDDEN);

    gemm_split<0><<<dim3(NQKV / 128, M / 128), 256, 0, stream>>>(
        Xhi, Xlo, WqkvHi, WqkvLo, bq, bk, bv, (void*)QKVb, M, NQKV, HIDDEN);

    kvpack<<<dim3(SEQ / 64, NKV, BATCH), 256, 0, stream>>>(QKVb, Kf, Vf);

    attn_mfma4<<<dim3(SEQ / 64, NHEAD, BATCH), 512, 0, stream>>>(QKVb, Kf, Vf, CtxHi, CtxLo);

    // Wo transpose AFTER attention (WotHi aliases Kf)
    wtrans_split<<<dim3(16, 16), 256, 0, stream>>>(Wo, WotHi, WotLo, 0, 1024, HIDDEN);

    gemm_split<1><<<dim3(HIDDEN / 128, M / 128), 256, 0, stream>>>(
        CtxHi, CtxLo, WotHi, WotLo, bo, nullptr, nullptr, (void*)out, M, HIDDEN, HIDDEN);
}

// Round 7
// 247.120 us; speedup vs baseline: 1.3722x; 1.0589x over previous
//
#include <hip/hip_runtime.h>
#include <hip/hip_bf16.h>

#define HIDDEN 1024
#define NHEAD 16
#define NKV 4
#define HDIM 64
#define KVDIM 256
#define SEQ 2048
#define BATCH 2
#define NQKV 1536   // 1024 (Q) + 256 (K) + 256 (V)

typedef __attribute__((ext_vector_type(4)))  float f32x4;
typedef __attribute__((ext_vector_type(16))) float f32x16;
typedef __attribute__((ext_vector_type(8)))  short s16x8;

#if defined(__has_builtin)
#if __has_builtin(__builtin_amdgcn_exp2f)
#define EXP2F(x) __builtin_amdgcn_exp2f(x)
#else
#define EXP2F(x) exp2f(x)
#endif
#else
#define EXP2F(x) exp2f(x)
#endif

static __device__ __forceinline__ ushort f2bf(float f) {
    union { __hip_bfloat16 b; ushort u; } cv; cv.b = __float2bfloat16(f); return cv.u;
}
static __device__ __forceinline__ float bfu2f(ushort u) {
    union { float f; unsigned int i; } cv; cv.i = ((unsigned int)u) << 16; return cv.f;
}
static __device__ __forceinline__ void split2(float v, ushort& h, ushort& l) {
    h = f2bf(v); l = f2bf(v - bfu2f(h));
}
// pack two positive finite f32 into (lo,hi) bf16 pair, round-half-up
static __device__ __forceinline__ unsigned pack_rh2(float a, float b) {
    unsigned ua = __float_as_uint(a) + 0x8000u;
    unsigned ub = __float_as_uint(b) + 0x8000u;
    return (ua >> 16) | (ub & 0xFFFF0000u);
}
// async global->LDS, 16B per lane. LDS dest = wave-uniform base + lane*16.
static __device__ __forceinline__ void async16(const void* g, void* l) {
    __builtin_amdgcn_global_load_lds((__attribute__((address_space(1))) void*)g,
                                     (__attribute__((address_space(3))) void*)l, 16, 0, 0);
}

// ---------------------------------------------------------------------------
// X fp32 -> hi/lo bf16 planes (elementwise).
// ---------------------------------------------------------------------------
__global__ __launch_bounds__(256)
void split_x(const float* __restrict__ in, ushort* __restrict__ hi,
             ushort* __restrict__ lo)
{
    int i = blockIdx.x * 256 + threadIdx.x;
    float4 v = ((const float4*)in)[i];
    ushort4 h, l;
    split2(v.x, h.x, l.x); split2(v.y, h.y, l.y);
    split2(v.z, h.z, l.z); split2(v.w, h.w, l.w);
    ((ushort4*)hi)[i] = h;
    ((ushort4*)lo)[i] = l;
}

// ---------------------------------------------------------------------------
// W [K][N] fp32 -> transposed split planes T{hi,lo}[roff+n][k] bf16.
// ---------------------------------------------------------------------------
__global__ __launch_bounds__(256)
void wtrans_split(const float* __restrict__ W, ushort* __restrict__ Thi,
                  ushort* __restrict__ Tlo, int roff, int N, int K)
{
    __shared__ float T[64][65];
    const int n0 = blockIdx.x * 64, k0 = blockIdx.y * 64;
    const int tid = threadIdx.x;
#pragma unroll
    for (int it = 0; it < 4; it++) {
        int idx = tid + it * 256;
        int kk = idx >> 4, n4 = (idx & 15) * 4;
        float4 v = *(const float4*)(W + (size_t)(k0 + kk) * N + n0 + n4);
        T[kk][n4 + 0] = v.x; T[kk][n4 + 1] = v.y;
        T[kk][n4 + 2] = v.z; T[kk][n4 + 3] = v.w;
    }
    __syncthreads();
#pragma unroll
    for (int it = 0; it < 4; it++) {
        int idx = tid + it * 256;
        int n = idx >> 4, k4 = (idx & 15) * 4;
        ushort4 h4, l4;
        split2(T[k4 + 0][n], h4.x, l4.x);
        split2(T[k4 + 1][n], h4.y, l4.y);
        split2(T[k4 + 2][n], h4.z, l4.z);
        split2(T[k4 + 3][n], h4.w, l4.w);
        *(ushort4*)(Thi + (size_t)(roff + n0 + n) * K + k0 + k4) = h4;
        *(ushort4*)(Tlo + (size_t)(roff + n0 + n) * K + k0 + k4) = l4;
    }
}

// ---------------------------------------------------------------------------
// Split-bf16 MFMA GEMM (unchanged from round 3).
// MODE 0: bf16 out (QKV; Q cols scaled 0.125*log2e for exp2-domain softmax)
// MODE 1: fp32 out
// ---------------------------------------------------------------------------
template <int MODE>
__global__ __launch_bounds__(256)
void gemm_split(const ushort* __restrict__ Ahi, const ushort* __restrict__ Alo,
                const ushort* __restrict__ Bhi, const ushort* __restrict__ Blo,
                const float* __restrict__ b0, const float* __restrict__ b1,
                const float* __restrict__ b2, void* __restrict__ Cout,
                int M, int N, int K)
{
    __shared__ __align__(16) ushort Ah[128 * 32];
    __shared__ __align__(16) ushort Al[128 * 32];
    __shared__ __align__(16) ushort Bh[128 * 32];
    __shared__ __align__(16) ushort Bl[128 * 32];

    const int tid = threadIdx.x;
    const int lane = tid & 63, wv = tid >> 6;
    const int wr = wv >> 1, wc = wv & 1;
    const int m = lane & 15, c = lane >> 4;
    const int row0 = blockIdx.y * 128, col0 = blockIdx.x * 128;

    const ushort* gA0[2]; const ushort* gA1[2];
    const ushort* gB0[2]; const ushort* gB1[2];
    int ldsOff[2];
#pragma unroll
    for (int it = 0; it < 2; it++) {
        int idx = it * 256 + tid;
        int r = idx >> 2, cb = (idx & 3) * 8;
        gA0[it] = Ahi + (size_t)(row0 + r) * K + cb;
        gA1[it] = Alo + (size_t)(row0 + r) * K + cb;
        gB0[it] = Bhi + (size_t)(col0 + r) * K + cb;
        gB1[it] = Blo + (size_t)(col0 + r) * K + cb;
        ldsOff[it] = (it * 256 + wv * 64) * 8;
    }

    f32x4 acc[4][4];
#pragma unroll
    for (int t = 0; t < 4; t++)
#pragma unroll
        for (int u = 0; u < 4; u++) acc[t][u] = (f32x4){0.f, 0.f, 0.f, 0.f};

    for (int k0 = 0; k0 < K; k0 += 32) {
        __syncthreads();
#pragma unroll
        for (int it = 0; it < 2; it++) {
            async16(gA0[it] + k0, Ah + ldsOff[it]);
            async16(gA1[it] + k0, Al + ldsOff[it]);
            async16(gB0[it] + k0, Bh + ldsOff[it]);
            async16(gB1[it] + k0, Bl + ldsOff[it]);
        }
        __syncthreads();

        s16x8 ah[4], al[4], bh[4], bl[4];
#pragma unroll
        for (int t = 0; t < 4; t++) {
            int ra = (64 * wr + 16 * t + m) * 32 + c * 8;
            int rb = (64 * wc + 16 * t + m) * 32 + c * 8;
            ah[t] = *(const s16x8*)&Ah[ra];
            al[t] = *(const s16x8*)&Al[ra];
            bh[t] = *(const s16x8*)&Bh[rb];
            bl[t] = *(const s16x8*)&Bl[rb];
        }
#pragma unroll
        for (int t = 0; t < 4; t++)
#pragma unroll
            for (int u = 0; u < 4; u++) {
                acc[t][u] = __builtin_amdgcn_mfma_f32_16x16x32_bf16(ah[t], bh[u], acc[t][u], 0, 0, 0);
                acc[t][u] = __builtin_amdgcn_mfma_f32_16x16x32_bf16(ah[t], bl[u], acc[t][u], 0, 0, 0);
                acc[t][u] = __builtin_amdgcn_mfma_f32_16x16x32_bf16(al[t], bh[u], acc[t][u], 0, 0, 0);
            }
    }

    const int orow = row0 + 64 * wr + 4 * c;
    const int ocol = col0 + 64 * wc + m;
    if (MODE == 0) {
        ushort* Cb = (ushort*)Cout;
#pragma unroll
        for (int u = 0; u < 4; u++) {
            int n = ocol + 16 * u;
            float bias, scl;
            if (n < 1024)      { bias = b0[n];        scl = 0.18033688f; }  // 0.125*log2(e)
            else if (n < 1280) { bias = b1[n - 1024]; scl = 1.0f; }
            else               { bias = b2[n - 1280]; scl = 1.0f; }
#pragma unroll
            for (int t = 0; t < 4; t++)
#pragma unroll
                for (int r = 0; r < 4; r++)
                    Cb[(size_t)(orow + 16 * t + r) * N + n] = f2bf((acc[t][u][r] + bias) * scl);
        }
    } else {
        float* Cf = (float*)Cout;
#pragma unroll
        for (int u = 0; u < 4; u++) {
            int n = ocol + 16 * u;
            float bias = b0[n];
#pragma unroll
            for (int t = 0; t < 4; t++)
#pragma unroll
                for (int r = 0; r < 4; r++)
                    Cf[(size_t)(orow + 16 * t + r) * N + n] = acc[t][u][r] + bias;
        }
    }
}

// ---------------------------------------------------------------------------
// Pack K and V (bf16 cols of QKV) into fragment-major buffers (unchanged).
// ---------------------------------------------------------------------------
__global__ __launch_bounds__(256)
void kvpack(const ushort* __restrict__ QKV, ushort* __restrict__ Kf,
            ushort* __restrict__ Vf)
{
    __shared__ __align__(16) ushort Kt[64][72];
    __shared__ __align__(16) ushort Vt[64][72];
    const int kt = blockIdx.x, hk = blockIdx.y, b = blockIdx.z;
    const int tid = threadIdx.x;

#pragma unroll
    for (int it = 0; it < 2; it++) {
        int idx = tid + it * 256;
        int r = idx >> 3, c8 = (idx & 7) * 8;
        const ushort* src = QKV + (size_t)(b * SEQ + kt * 64 + r) * NQKV + hk * HDIM + c8;
        *(s16x8*)&Kt[r][c8] = *(const s16x8*)(src + 1024);
        *(s16x8*)&Vt[r][c8] = *(const s16x8*)(src + 1280);
    }
    __syncthreads();

#pragma unroll
    for (int it = 0; it < 2; it++) {
        int idx = tid + it * 256;
        int t32 = idx >> 8, kc = (idx >> 6) & 3, lane = idx & 63;
        int n32 = lane & 31, h5 = lane >> 5;
        s16x8 fr = *(const s16x8*)&Kt[t32 * 32 + n32][kc * 16 + h5 * 8];
        size_t flat = ((size_t)(((b * NKV + hk) * 64 + kt * 2 + t32) * 4 + kc) * 64 + lane) * 8;
        *(s16x8*)(Kf + flat) = fr;
    }
#pragma unroll
    for (int it = 0; it < 2; it++) {
        int idx = tid + it * 256;
        int kcdn = idx >> 6, lane = idx & 63;
        int kc = kcdn >> 1, dn = kcdn & 1;
        int n32 = lane & 31, h5 = lane >> 5;
        s16x8 fr;
#pragma unroll
        for (int j = 0; j < 8; j++)
            fr[j] = (short)Vt[kc * 16 + h5 * 8 + j][dn * 32 + n32];
        size_t flat = ((size_t)(((b * NKV + hk) * 32 + kt) * 8 + kc * 2 + dn) * 64 + lane) * 8;
        *(s16x8*)(Vf + flat) = fr;
    }
}

// ---------------------------------------------------------------------------
// Flash attention v5: round-6 pipeline + S^T score layout.
// QK MFMA computes S^T (A=K, B=Q) so C-layout gives col=q(=lane&31),
// row=key=(reg&3)+8*(reg>>2)+4*(lane>>5): each lane owns ONE q-row and 16
// keys in quads of 4 consecutive -> P stores become 8 ds_write_b64 of packed
// bf16 pairs per kt (was 32 ds_write_b16). l is summed in-register per lane
// (one q-row) -> the ones-column MFMA is gone (loop MFMA 160->128 cyc/iter).
// PV step and Kf/Vf layouts unchanged (verified rounds 5/6).
// ---------------------------------------------------------------------------
__global__ __launch_bounds__(512, 2)
void attn_mfma5(const ushort* __restrict__ QKV, const ushort* __restrict__ Kf,
                const ushort* __restrict__ Vf,
                ushort* __restrict__ Chi, ushort* __restrict__ Clo)
{
    __shared__ __align__(16) ushort Ps[8][32][72];   // 36,864 B; merge bufs alias
    float* OLb = (float*)&Ps[0][0][0];               // [4][32][64] = 32,768 B
    float* LLb = (float*)((char*)&Ps[0][0][0] + 33024);  // [4][32]

    const int tid = threadIdx.x, w = tid >> 6, lane = tid & 63;
    const int g = w >> 2, ws_ = w & 3;               // q-group, kt-split index
    const int n32 = lane & 31, h5 = lane >> 5;
    const int h = blockIdx.y, b = blockIdx.z, hk = h >> 2;
    const int q0 = blockIdx.x * 64 + g * 32;

    // Q A/B-fragments (4 k-chunks of 16), hoisted
    const ushort* qrow = QKV + (size_t)(b * SEQ + q0 + n32) * NQKV + h * HDIM + h5 * 8;
    s16x8 aq[4];
#pragma unroll
    for (int kc = 0; kc < 4; kc++) aq[kc] = *(const s16x8*)(qrow + kc * 16);

    f32x16 accO[2];
#pragma unroll
    for (int j = 0; j < 16; j++) { accO[0][j] = 0.f; accO[1][j] = 0.f; }
    float lacc = 0.f;

    const ushort* kf0 = Kf + (size_t)(b * NKV + hk) * (64 * 4 * 64 * 8) + (size_t)lane * 8;
    const ushort* vf0 = Vf + (size_t)(b * NKV + hk) * (32 * 8 * 64 * 8) + (size_t)lane * 8;

    s16x8 kreg[8], vreg[8];

#define LOAD_K(kt_) do {                                                      \
    _Pragma("unroll")                                                         \
    for (int kn = 0; kn < 2; kn++)                                            \
        _Pragma("unroll")                                                     \
        for (int kc = 0; kc < 4; kc++)                                        \
            kreg[kn * 4 + kc] =                                               \
                *(const s16x8*)(kf0 + (size_t)(((kt_) * 2 + kn) * 4 + kc) * 512); \
} while (0)

#define LOAD_V(kt_) do {                                                      \
    _Pragma("unroll")                                                         \
    for (int kc = 0; kc < 4; kc++)                                            \
        _Pragma("unroll")                                                     \
        for (int dn = 0; dn < 2; dn++)                                        \
            vreg[kc * 2 + dn] =                                               \
                *(const s16x8*)(vf0 + (size_t)((kt_) * 8 + kc * 2 + dn) * 512); \
} while (0)

// S^T = K Q^T: lane owns q=n32; key(reg) = kn*32 + (reg&3) + 8*(reg>>2) + 4*h5.
// exp2 in log2 domain (log2e folded into Q), in-register l sum, packed stores.
#define QK_EXP_STORE() do {                                                   \
    _Pragma("unroll")                                                         \
    for (int kn = 0; kn < 2; kn++) {                                          \
        f32x16 S;                                                             \
        _Pragma("unroll")                                                     \
        for (int j = 0; j < 16; j++) S[j] = 0.f;                              \
        _Pragma("unroll")                                                     \
        for (int kc = 0; kc < 4; kc++)                                        \
            S = __builtin_amdgcn_mfma_f32_32x32x16_bf16(kreg[kn * 4 + kc],    \
                    aq[kc], S, 0, 0, 0);                                      \
        float p[16];                                                          \
        _Pragma("unroll")                                                     \
        for (int reg = 0; reg < 16; reg++) {                                  \
            p[reg] = EXP2F(S[reg]);                                           \
            lacc += p[reg];                                                   \
        }                                                                     \
        _Pragma("unroll")                                                     \
        for (int t = 0; t < 4; t++) {                                         \
            uint2 pk;                                                         \
            pk.x = pack_rh2(p[4 * t + 0], p[4 * t + 1]);                      \
            pk.y = pack_rh2(p[4 * t + 2], p[4 * t + 3]);                      \
            *(uint2*)&Ps[w][n32][kn * 32 + 8 * t + 4 * h5] = pk;              \
        }                                                                     \
    }                                                                         \
} while (0)

#define PV_STEP() do {                                                        \
    s16x8 pa[4];                                                              \
    _Pragma("unroll")                                                         \
    for (int kc = 0; kc < 4; kc++)                                            \
        pa[kc] = *(const s16x8*)&Ps[w][n32][kc * 16 + h5 * 8];                \
    _Pragma("unroll")                                                         \
    for (int kc = 0; kc < 4; kc++) {                                          \
        _Pragma("unroll")                                                     \
        for (int dn = 0; dn < 2; dn++)                                        \
            accO[dn] = __builtin_amdgcn_mfma_f32_32x32x16_bf16(pa[kc],        \
                           vreg[kc * 2 + dn], accO[dn], 0, 0, 0);             \
    }                                                                         \
} while (0)

    // prologue: first tile's scores
    LOAD_K(ws_);
    QK_EXP_STORE();

    for (int i = 1; i < 8; i++) {
        const int ktc = ws_ + 4 * i;
        LOAD_V(ktc - 4);     // V for previous tile (issued first: partial vm wait)
        LOAD_K(ktc);         // K for current tile
        PV_STEP();           // PV(prev): reads Ps BEFORE the writes below (in-order DS)
        QK_EXP_STORE();      // scores(cur) + overwrite Ps
    }

    // epilogue: last tile's PV
    LOAD_V(ws_ + 28);
    PV_STEP();

#undef LOAD_K
#undef LOAD_V
#undef QK_EXP_STORE
#undef PV_STEP

    // complete l across the two h5 halves (each summed 16 of 32 keys/tile)
    lacc += __shfl_xor(lacc, 32);

    __syncthreads();   // everyone done with Ps — safe to alias merge buffers

    const int qq = tid >> 4;          // 0..31
    const int d0 = (tid & 15) * 4;    // 0..60
#pragma unroll
    for (int phase = 0; phase < 2; phase++) {
        if (g == phase) {
#pragma unroll
            for (int reg = 0; reg < 16; reg++) {
                int q = (reg & 3) + 8 * (reg >> 2) + 4 * h5;
                OLb[(ws_ * 32 + q) * 64 + n32]      = accO[0][reg];
                OLb[(ws_ * 32 + q) * 64 + 32 + n32] = accO[1][reg];
            }
            if (h5 == 0) LLb[ws_ * 32 + n32] = lacc;
        }
        __syncthreads();
        {
            float lsum = LLb[qq] + LLb[32 + qq] + LLb[64 + qq] + LLb[96 + qq];
            float inv = 1.f / lsum;
            float o[4];
#pragma unroll
            for (int e = 0; e < 4; e++)
                o[e] = (OLb[(0 * 32 + qq) * 64 + d0 + e] + OLb[(1 * 32 + qq) * 64 + d0 + e] +
                        OLb[(2 * 32 + qq) * 64 + d0 + e] + OLb[(3 * 32 + qq) * 64 + d0 + e]) * inv;
            ushort4 hs, ls;
            split2(o[0], hs.x, ls.x); split2(o[1], hs.y, ls.y);
            split2(o[2], hs.z, ls.z); split2(o[3], hs.w, ls.w);
            size_t off = (size_t)(b * SEQ + blockIdx.x * 64 + phase * 32 + qq) * HIDDEN
                       + h * HDIM + d0;
            *(ushort4*)(Chi + off) = hs;
            *(ushort4*)(Clo + off) = ls;
        }
        __syncthreads();   // before next phase overwrites merge buffers
    }
}

// ---------------------------------------------------------------------------
extern "C" void kernel_launch(void* const* d_in, const int* in_sizes, int n_in,
                              void* d_out, int out_size, void* d_ws, size_t ws_size,
                              hipStream_t stream)
{
    const float* X  = (const float*)d_in[0];
    const float* Wq = (const float*)d_in[1];
    const float* bq = (const float*)d_in[2];
    const float* Wk = (const float*)d_in[3];
    const float* bk = (const float*)d_in[4];
    const float* Wv = (const float*)d_in[5];
    const float* bv = (const float*)d_in[6];
    const float* Wo = (const float*)d_in[7];
    const float* bo = (const float*)d_in[8];
    float* out = (float*)d_out;

    const int M = BATCH * SEQ;  // 4096
    // ws layout (40 MB): Xhi/CtxHi 8 | Xlo/CtxLo 8 | QKVb 12 | WqkvHi 3 | WqkvLo 3
    // | Kf 2 (aliases WotHi: Wo transpose runs AFTER attention) | WotLo 2 | Vf 2
    char* ws = (char*)d_ws;
    ushort* Xhi    = (ushort*)(ws);
    ushort* Xlo    = (ushort*)(ws + (8u  << 20));
    ushort* CtxHi  = Xhi;
    ushort* CtxLo  = Xlo;
    ushort* QKVb   = (ushort*)(ws + (16u << 20));
    ushort* WqkvHi = (ushort*)(ws + (28u << 20));
    ushort* WqkvLo = (ushort*)(ws + (31u << 20));
    ushort* Kf     = (ushort*)(ws + (34u << 20));   // lives until attention ends
    ushort* WotHi  = (ushort*)(ws + (34u << 20));   // written after attention
    ushort* WotLo  = (ushort*)(ws + (36u << 20));
    ushort* Vf     = (ushort*)(ws + (38u << 20));

    split_x<<<dim3(M * HIDDEN / 4 / 256), 256, 0, stream>>>(X, Xhi, Xlo);
    wtrans_split<<<dim3(16, 16), 256, 0, stream>>>(Wq, WqkvHi, WqkvLo, 0,    1024, HIDDEN);
    wtrans_split<<<dim3(4, 16),  256, 0, stream>>>(Wk, WqkvHi, WqkvLo, 1024, 256,  HIDDEN);
    wtrans_split<<<dim3(4, 16),  256, 0, stream>>>(Wv, WqkvHi, WqkvLo, 1280, 256,  HIDDEN);

    gemm_split<0><<<dim3(NQKV / 128, M / 128), 256, 0, stream>>>(
        Xhi, Xlo, WqkvHi, WqkvLo, bq, bk, bv, (void*)QKVb, M, NQKV, HIDDEN);

    kvpack<<<dim3(SEQ / 64, NKV, BATCH), 256, 0, stream>>>(QKVb, Kf, Vf);

    attn_mfma5<<<dim3(SEQ / 64, NHEAD, BATCH), 512, 0, stream>>>(QKVb, Kf, Vf, CtxHi, CtxLo);

    // Wo transpose AFTER attention (WotHi aliases Kf)
    wtrans_split<<<dim3(16, 16), 256, 0, stream>>>(Wo, WotHi, WotLo, 0, 1024, HIDDEN);

    gemm_split<1><<<dim3(HIDDEN / 128, M / 128), 256, 0, stream>>>(
        CtxHi, CtxLo, WotHi, WotLo, bo, nullptr, nullptr, (void*)out, M, HIDDEN, HIDDEN);
}

// Round 8
// 241.263 us; speedup vs baseline: 1.4055x; 1.0243x over previous
//
#include <hip/hip_runtime.h>
#include <hip/hip_bf16.h>

#define HIDDEN 1024
#define NHEAD 16
#define NKV 4
#define HDIM 64
#define KVDIM 256
#define SEQ 2048
#define BATCH 2
#define NQKV 1536   // 1024 (Q) + 256 (K) + 256 (V)

typedef __attribute__((ext_vector_type(4)))  float f32x4;
typedef __attribute__((ext_vector_type(16))) float f32x16;
typedef __attribute__((ext_vector_type(8)))  short s16x8;
typedef __attribute__((ext_vector_type(4)))  short s16x4;

#if defined(__has_builtin)
#if __has_builtin(__builtin_amdgcn_exp2f)
#define EXP2F(x) __builtin_amdgcn_exp2f(x)
#else
#define EXP2F(x) exp2f(x)
#endif
#else
#define EXP2F(x) exp2f(x)
#endif

static __device__ __forceinline__ ushort f2bf(float f) {
    union { __hip_bfloat16 b; ushort u; } cv; cv.b = __float2bfloat16(f); return cv.u;
}
static __device__ __forceinline__ float bfu2f(ushort u) {
    union { float f; unsigned int i; } cv; cv.i = ((unsigned int)u) << 16; return cv.f;
}
static __device__ __forceinline__ void split2(float v, ushort& h, ushort& l) {
    h = f2bf(v); l = f2bf(v - bfu2f(h));
}
// pack two positive finite f32 into (lo,hi) bf16 pair, round-half-up
static __device__ __forceinline__ unsigned pack_rh2(float a, float b) {
    unsigned ua = __float_as_uint(a) + 0x8000u;
    unsigned ub = __float_as_uint(b) + 0x8000u;
    return (ua >> 16) | (ub & 0xFFFF0000u);
}
// async global->LDS, 16B per lane. LDS dest = wave-uniform base + lane*16.
static __device__ __forceinline__ void async16(const void* g, void* l) {
    __builtin_amdgcn_global_load_lds((__attribute__((address_space(1))) void*)g,
                                     (__attribute__((address_space(3))) void*)l, 16, 0, 0);
}

// ---------------------------------------------------------------------------
// X fp32 -> hi/lo bf16 planes (elementwise).
// ---------------------------------------------------------------------------
__global__ __launch_bounds__(256)
void split_x(const float* __restrict__ in, ushort* __restrict__ hi,
             ushort* __restrict__ lo)
{
    int i = blockIdx.x * 256 + threadIdx.x;
    float4 v = ((const float4*)in)[i];
    ushort4 h, l;
    split2(v.x, h.x, l.x); split2(v.y, h.y, l.y);
    split2(v.z, h.z, l.z); split2(v.w, h.w, l.w);
    ((ushort4*)hi)[i] = h;
    ((ushort4*)lo)[i] = l;
}

// ---------------------------------------------------------------------------
// W [K][N] fp32 -> transposed split planes T{hi,lo}[roff+n][k] bf16.
// ---------------------------------------------------------------------------
__global__ __launch_bounds__(256)
void wtrans_split(const float* __restrict__ W, ushort* __restrict__ Thi,
                  ushort* __restrict__ Tlo, int roff, int N, int K)
{
    __shared__ float T[64][65];
    const int n0 = blockIdx.x * 64, k0 = blockIdx.y * 64;
    const int tid = threadIdx.x;
#pragma unroll
    for (int it = 0; it < 4; it++) {
        int idx = tid + it * 256;
        int kk = idx >> 4, n4 = (idx & 15) * 4;
        float4 v = *(const float4*)(W + (size_t)(k0 + kk) * N + n0 + n4);
        T[kk][n4 + 0] = v.x; T[kk][n4 + 1] = v.y;
        T[kk][n4 + 2] = v.z; T[kk][n4 + 3] = v.w;
    }
    __syncthreads();
#pragma unroll
    for (int it = 0; it < 4; it++) {
        int idx = tid + it * 256;
        int n = idx >> 4, k4 = (idx & 15) * 4;
        ushort4 h4, l4;
        split2(T[k4 + 0][n], h4.x, l4.x);
        split2(T[k4 + 1][n], h4.y, l4.y);
        split2(T[k4 + 2][n], h4.z, l4.z);
        split2(T[k4 + 3][n], h4.w, l4.w);
        *(ushort4*)(Thi + (size_t)(roff + n0 + n) * K + k0 + k4) = h4;
        *(ushort4*)(Tlo + (size_t)(roff + n0 + n) * K + k0 + k4) = l4;
    }
}

// ---------------------------------------------------------------------------
// Split-bf16 MFMA GEMM, 64x128 tile (M x N), BK=32, 4 waves in 2x2.
// Tile shrunk from 128x128 so grids reach >=2 blocks/CU:
//   QKV: 12x64 = 768 blocks (3/CU), O-proj: 8x64 = 512 (2/CU) — the 128-tile
//   grids were 1-1.5/CU, leaving barrier drains fully exposed.
// Each wave: 32x64 out = 2x4 grid of 16x16x32 MFMAs x 3 split terms.
// MODE 0: bf16 out (QKV; Q cols scaled 0.125*log2e). MODE 1: fp32 out.
// ---------------------------------------------------------------------------
template <int MODE>
__global__ __launch_bounds__(256)
void gemm_split(const ushort* __restrict__ Ahi, const ushort* __restrict__ Alo,
                const ushort* __restrict__ Bhi, const ushort* __restrict__ Blo,
                const float* __restrict__ b0, const float* __restrict__ b1,
                const float* __restrict__ b2, void* __restrict__ Cout,
                int M, int N, int K)
{
    __shared__ __align__(16) ushort Ah[64 * 32];
    __shared__ __align__(16) ushort Al[64 * 32];
    __shared__ __align__(16) ushort Bh[128 * 32];
    __shared__ __align__(16) ushort Bl[128 * 32];

    const int tid = threadIdx.x;
    const int lane = tid & 63, wv = tid >> 6;
    const int wr = wv >> 1, wc = wv & 1;
    const int m = lane & 15, c = lane >> 4;
    const int row0 = blockIdx.y * 64, col0 = blockIdx.x * 128;

    // A staging: one 16B slot/thread (64x32 = 256 slots)
    const ushort* gA0 = Ahi + (size_t)(row0 + (tid >> 2)) * K + (tid & 3) * 8;
    const ushort* gA1 = Alo + (size_t)(row0 + (tid >> 2)) * K + (tid & 3) * 8;
    const int ldsA = tid * 8;
    // B staging: two slots/thread (128x32 = 512 slots)
    const ushort* gB0[2]; const ushort* gB1[2];
    int ldsB[2];
#pragma unroll
    for (int it = 0; it < 2; it++) {
        int idx = it * 256 + tid;
        gB0[it] = Bhi + (size_t)(col0 + (idx >> 2)) * K + (idx & 3) * 8;
        gB1[it] = Blo + (size_t)(col0 + (idx >> 2)) * K + (idx & 3) * 8;
        ldsB[it] = idx * 8;
    }

    f32x4 acc[2][4];
#pragma unroll
    for (int t = 0; t < 2; t++)
#pragma unroll
        for (int u = 0; u < 4; u++) acc[t][u] = (f32x4){0.f, 0.f, 0.f, 0.f};

    for (int k0 = 0; k0 < K; k0 += 32) {
        __syncthreads();
        async16(gA0 + k0, Ah + ldsA);
        async16(gA1 + k0, Al + ldsA);
#pragma unroll
        for (int it = 0; it < 2; it++) {
            async16(gB0[it] + k0, Bh + ldsB[it]);
            async16(gB1[it] + k0, Bl + ldsB[it]);
        }
        __syncthreads();

        s16x8 ah[2], al[2], bh[4], bl[4];
#pragma unroll
        for (int t = 0; t < 2; t++) {
            int ra = (wr * 32 + t * 16 + m) * 32 + c * 8;
            ah[t] = *(const s16x8*)&Ah[ra];
            al[t] = *(const s16x8*)&Al[ra];
        }
#pragma unroll
        for (int u = 0; u < 4; u++) {
            int rb = (wc * 64 + u * 16 + m) * 32 + c * 8;
            bh[u] = *(const s16x8*)&Bh[rb];
            bl[u] = *(const s16x8*)&Bl[rb];
        }
#pragma unroll
        for (int t = 0; t < 2; t++)
#pragma unroll
            for (int u = 0; u < 4; u++) {
                acc[t][u] = __builtin_amdgcn_mfma_f32_16x16x32_bf16(ah[t], bh[u], acc[t][u], 0, 0, 0);
                acc[t][u] = __builtin_amdgcn_mfma_f32_16x16x32_bf16(ah[t], bl[u], acc[t][u], 0, 0, 0);
                acc[t][u] = __builtin_amdgcn_mfma_f32_16x16x32_bf16(al[t], bh[u], acc[t][u], 0, 0, 0);
            }
    }

    const int orow = row0 + wr * 32 + 4 * c;   // + 16t + r
    const int ocol = col0 + wc * 64 + m;       // + 16u
    if (MODE == 0) {
        ushort* Cb = (ushort*)Cout;
#pragma unroll
        for (int u = 0; u < 4; u++) {
            int n = ocol + 16 * u;
            float bias, scl;
            if (n < 1024)      { bias = b0[n];        scl = 0.18033688f; }  // 0.125*log2(e)
            else if (n < 1280) { bias = b1[n - 1024]; scl = 1.0f; }
            else               { bias = b2[n - 1280]; scl = 1.0f; }
#pragma unroll
            for (int t = 0; t < 2; t++)
#pragma unroll
                for (int r = 0; r < 4; r++)
                    Cb[(size_t)(orow + 16 * t + r) * N + n] = f2bf((acc[t][u][r] + bias) * scl);
        }
    } else {
        float* Cf = (float*)Cout;
#pragma unroll
        for (int u = 0; u < 4; u++) {
            int n = ocol + 16 * u;
            float bias = b0[n];
#pragma unroll
            for (int t = 0; t < 2; t++)
#pragma unroll
                for (int r = 0; r < 4; r++)
                    Cf[(size_t)(orow + 16 * t + r) * N + n] = acc[t][u][r] + bias;
        }
    }
}

// ---------------------------------------------------------------------------
// Pack K and V (bf16 cols of QKV) into fragment-major buffers (unchanged).
// ---------------------------------------------------------------------------
__global__ __launch_bounds__(256)
void kvpack(const ushort* __restrict__ QKV, ushort* __restrict__ Kf,
            ushort* __restrict__ Vf)
{
    __shared__ __align__(16) ushort Kt[64][72];
    __shared__ __align__(16) ushort Vt[64][72];
    const int kt = blockIdx.x, hk = blockIdx.y, b = blockIdx.z;
    const int tid = threadIdx.x;

#pragma unroll
    for (int it = 0; it < 2; it++) {
        int idx = tid + it * 256;
        int r = idx >> 3, c8 = (idx & 7) * 8;
        const ushort* src = QKV + (size_t)(b * SEQ + kt * 64 + r) * NQKV + hk * HDIM + c8;
        *(s16x8*)&Kt[r][c8] = *(const s16x8*)(src + 1024);
        *(s16x8*)&Vt[r][c8] = *(const s16x8*)(src + 1280);
    }
    __syncthreads();

#pragma unroll
    for (int it = 0; it < 2; it++) {
        int idx = tid + it * 256;
        int t32 = idx >> 8, kc = (idx >> 6) & 3, lane = idx & 63;
        int n32 = lane & 31, h5 = lane >> 5;
        s16x8 fr = *(const s16x8*)&Kt[t32 * 32 + n32][kc * 16 + h5 * 8];
        size_t flat = ((size_t)(((b * NKV + hk) * 64 + kt * 2 + t32) * 4 + kc) * 64 + lane) * 8;
        *(s16x8*)(Kf + flat) = fr;
    }
#pragma unroll
    for (int it = 0; it < 2; it++) {
        int idx = tid + it * 256;
        int kcdn = idx >> 6, lane = idx & 63;
        int kc = kcdn >> 1, dn = kcdn & 1;
        int n32 = lane & 31, h5 = lane >> 5;
        s16x8 fr;
#pragma unroll
        for (int j = 0; j < 8; j++)
            fr[j] = (short)Vt[kc * 16 + h5 * 8 + j][dn * 32 + n32];
        size_t flat = ((size_t)(((b * NKV + hk) * 32 + kt) * 8 + kc * 2 + dn) * 64 + lane) * 8;
        *(s16x8*)(Vf + flat) = fr;
    }
}

// ---------------------------------------------------------------------------
// Flash attention v6 = v5 + (a) Ps stride 68 ushorts (34 banks: b64 writes
// and b64 reads both 2-way = free, kills r7's 2.1M conflict cycles at
// stride 72) and (b) l via ones-column MFMA (accl) instead of 32 in-register
// fadds/iter — shifts 64 VALU cyc to the 78%-idle MFMA pipe.
// ---------------------------------------------------------------------------
__global__ __launch_bounds__(512, 2)
void attn_mfma6(const ushort* __restrict__ QKV, const ushort* __restrict__ Kf,
                const ushort* __restrict__ Vf,
                ushort* __restrict__ Chi, ushort* __restrict__ Clo)
{
    __shared__ __align__(16) ushort Ps[8][32][68];   // 34,816 B; merge bufs alias
    float* OLb = (float*)&Ps[0][0][0];               // [4][32][64] = 32,768 B
    float* LLb = (float*)((char*)&Ps[0][0][0] + 33024);  // [4][32]

    const int tid = threadIdx.x, w = tid >> 6, lane = tid & 63;
    const int g = w >> 2, ws_ = w & 3;               // q-group, kt-split index
    const int n32 = lane & 31, h5 = lane >> 5;
    const int h = blockIdx.y, b = blockIdx.z, hk = h >> 2;
    const int q0 = blockIdx.x * 64 + g * 32;

    // Q B-fragments (4 k-chunks of 16), hoisted
    const ushort* qrow = QKV + (size_t)(b * SEQ + q0 + n32) * NQKV + h * HDIM + h5 * 8;
    s16x8 aq[4];
#pragma unroll
    for (int kc = 0; kc < 4; kc++) aq[kc] = *(const s16x8*)(qrow + kc * 16);

    f32x16 accO[2], accl;
#pragma unroll
    for (int j = 0; j < 16; j++) { accO[0][j] = 0.f; accO[1][j] = 0.f; accl[j] = 0.f; }

    s16x8 ones;
#pragma unroll
    for (int j = 0; j < 8; j++) ones[j] = (short)0x3F80;   // bf16 1.0

    const ushort* kf0 = Kf + (size_t)(b * NKV + hk) * (64 * 4 * 64 * 8) + (size_t)lane * 8;
    const ushort* vf0 = Vf + (size_t)(b * NKV + hk) * (32 * 8 * 64 * 8) + (size_t)lane * 8;

    s16x8 kreg[8], vreg[8];

#define LOAD_K(kt_) do {                                                      \
    _Pragma("unroll")                                                         \
    for (int kn = 0; kn < 2; kn++)                                            \
        _Pragma("unroll")                                                     \
        for (int kc = 0; kc < 4; kc++)                                        \
            kreg[kn * 4 + kc] =                                               \
                *(const s16x8*)(kf0 + (size_t)(((kt_) * 2 + kn) * 4 + kc) * 512); \
} while (0)

#define LOAD_V(kt_) do {                                                      \
    _Pragma("unroll")                                                         \
    for (int kc = 0; kc < 4; kc++)                                            \
        _Pragma("unroll")                                                     \
        for (int dn = 0; dn < 2; dn++)                                        \
            vreg[kc * 2 + dn] =                                               \
                *(const s16x8*)(vf0 + (size_t)((kt_) * 8 + kc * 2 + dn) * 512); \
} while (0)

// S^T = K Q^T: lane owns q=n32; key(reg) = kn*32 + (reg&3) + 8*(reg>>2) + 4*h5.
// exp2 in log2 domain (log2e folded into Q), packed b64 stores.
#define QK_EXP_STORE() do {                                                   \
    _Pragma("unroll")                                                         \
    for (int kn = 0; kn < 2; kn++) {                                          \
        f32x16 S;                                                             \
        _Pragma("unroll")                                                     \
        for (int j = 0; j < 16; j++) S[j] = 0.f;                              \
        _Pragma("unroll")                                                     \
        for (int kc = 0; kc < 4; kc++)                                        \
            S = __builtin_amdgcn_mfma_f32_32x32x16_bf16(kreg[kn * 4 + kc],    \
                    aq[kc], S, 0, 0, 0);                                      \
        float p[16];                                                          \
        _Pragma("unroll")                                                     \
        for (int reg = 0; reg < 16; reg++) p[reg] = EXP2F(S[reg]);            \
        _Pragma("unroll")                                                     \
        for (int t = 0; t < 4; t++) {                                         \
            uint2 pk;                                                         \
            pk.x = pack_rh2(p[4 * t + 0], p[4 * t + 1]);                      \
            pk.y = pack_rh2(p[4 * t + 2], p[4 * t + 3]);                      \
            *(uint2*)&Ps[w][n32][kn * 32 + 8 * t + 4 * h5] = pk;              \
        }                                                                     \
    }                                                                         \
} while (0)

#define PV_STEP() do {                                                        \
    s16x8 pa[4];                                                              \
    _Pragma("unroll")                                                         \
    for (int kc = 0; kc < 4; kc++) {                                          \
        s16x4 lo4 = *(const s16x4*)&Ps[w][n32][kc * 16 + h5 * 8];             \
        s16x4 hi4 = *(const s16x4*)&Ps[w][n32][kc * 16 + h5 * 8 + 4];         \
        pa[kc] = __builtin_shufflevector(lo4, hi4, 0, 1, 2, 3, 4, 5, 6, 7);   \
    }                                                                         \
    _Pragma("unroll")                                                         \
    for (int kc = 0; kc < 4; kc++) {                                          \
        accl = __builtin_amdgcn_mfma_f32_32x32x16_bf16(pa[kc], ones, accl, 0, 0, 0); \
        _Pragma("unroll")                                                     \
        for (int dn = 0; dn < 2; dn++)                                        \
            accO[dn] = __builtin_amdgcn_mfma_f32_32x32x16_bf16(pa[kc],        \
                           vreg[kc * 2 + dn], accO[dn], 0, 0, 0);             \
    }                                                                         \
} while (0)

    // prologue: first tile's scores
    LOAD_K(ws_);
    QK_EXP_STORE();

    for (int i = 1; i < 8; i++) {
        const int ktc = ws_ + 4 * i;
        LOAD_V(ktc - 4);     // V for previous tile (issued first: partial vm wait)
        LOAD_K(ktc);         // K for current tile
        PV_STEP();           // PV(prev): reads Ps BEFORE the writes below (in-order DS)
        QK_EXP_STORE();      // scores(cur) + overwrite Ps
    }

    // epilogue: last tile's PV
    LOAD_V(ws_ + 28);
    PV_STEP();

#undef LOAD_K
#undef LOAD_V
#undef QK_EXP_STORE
#undef PV_STEP

    __syncthreads();   // everyone done with Ps — safe to alias merge buffers

    const int qq = tid >> 4;          // 0..31
    const int d0 = (tid & 15) * 4;    // 0..60
#pragma unroll
    for (int phase = 0; phase < 2; phase++) {
        if (g == phase) {
#pragma unroll
            for (int reg = 0; reg < 16; reg++) {
                int q = (reg & 3) + 8 * (reg >> 2) + 4 * h5;
                OLb[(ws_ * 32 + q) * 64 + n32]      = accO[0][reg];
                OLb[(ws_ * 32 + q) * 64 + 32 + n32] = accO[1][reg];
                if (n32 == 0) LLb[ws_ * 32 + q] = accl[reg];
            }
        }
        __syncthreads();
        {
            float lsum = LLb[qq] + LLb[32 + qq] + LLb[64 + qq] + LLb[96 + qq];
            float inv = 1.f / lsum;
            float o[4];
#pragma unroll
            for (int e = 0; e < 4; e++)
                o[e] = (OLb[(0 * 32 + qq) * 64 + d0 + e] + OLb[(1 * 32 + qq) * 64 + d0 + e] +
                        OLb[(2 * 32 + qq) * 64 + d0 + e] + OLb[(3 * 32 + qq) * 64 + d0 + e]) * inv;
            ushort4 hs, ls;
            split2(o[0], hs.x, ls.x); split2(o[1], hs.y, ls.y);
            split2(o[2], hs.z, ls.z); split2(o[3], hs.w, ls.w);
            size_t off = (size_t)(b * SEQ + blockIdx.x * 64 + phase * 32 + qq) * HIDDEN
                       + h * HDIM + d0;
            *(ushort4*)(Chi + off) = hs;
            *(ushort4*)(Clo + off) = ls;
        }
        __syncthreads();   // before next phase overwrites merge buffers
    }
}

// ---------------------------------------------------------------------------
extern "C" void kernel_launch(void* const* d_in, const int* in_sizes, int n_in,
                              void* d_out, int out_size, void* d_ws, size_t ws_size,
                              hipStream_t stream)
{
    const float* X  = (const float*)d_in[0];
    const float* Wq = (const float*)d_in[1];
    const float* bq = (const float*)d_in[2];
    const float* Wk = (const float*)d_in[3];
    const float* bk = (const float*)d_in[4];
    const float* Wv = (const float*)d_in[5];
    const float* bv = (const float*)d_in[6];
    const float* Wo = (const float*)d_in[7];
    const float* bo = (const float*)d_in[8];
    float* out = (float*)d_out;

    const int M = BATCH * SEQ;  // 4096
    // ws layout (40 MB): Xhi/CtxHi 8 | Xlo/CtxLo 8 | QKVb 12 | WqkvHi 3 | WqkvLo 3
    // | Kf 2 (aliases WotHi: Wo transpose runs AFTER attention) | WotLo 2 | Vf 2
    char* ws = (char*)d_ws;
    ushort* Xhi    = (ushort*)(ws);
    ushort* Xlo    = (ushort*)(ws + (8u  << 20));
    ushort* CtxHi  = Xhi;
    ushort* CtxLo  = Xlo;
    ushort* QKVb   = (ushort*)(ws + (16u << 20));
    ushort* WqkvHi = (ushort*)(ws + (28u << 20));
    ushort* WqkvLo = (ushort*)(ws + (31u << 20));
    ushort* Kf     = (ushort*)(ws + (34u << 20));   // lives until attention ends
    ushort* WotHi  = (ushort*)(ws + (34u << 20));   // written after attention
    ushort* WotLo  = (ushort*)(ws + (36u << 20));
    ushort* Vf     = (ushort*)(ws + (38u << 20));

    split_x<<<dim3(M * HIDDEN / 4 / 256), 256, 0, stream>>>(X, Xhi, Xlo);
    wtrans_split<<<dim3(16, 16), 256, 0, stream>>>(Wq, WqkvHi, WqkvLo, 0,    1024, HIDDEN);
    wtrans_split<<<dim3(4, 16),  256, 0, stream>>>(Wk, WqkvHi, WqkvLo, 1024, 256,  HIDDEN);
    wtrans_split<<<dim3(4, 16),  256, 0, stream>>>(Wv, WqkvHi, WqkvLo, 1280, 256,  HIDDEN);

    gemm_split<0><<<dim3(NQKV / 128, M / 64), 256, 0, stream>>>(
        Xhi, Xlo, WqkvHi, WqkvLo, bq, bk, bv, (void*)QKVb, M, NQKV, HIDDEN);

    kvpack<<<dim3(SEQ / 64, NKV, BATCH), 256, 0, stream>>>(QKVb, Kf, Vf);

    attn_mfma6<<<dim3(SEQ / 64, NHEAD, BATCH), 512, 0, stream>>>(QKVb, Kf, Vf, CtxHi, CtxLo);

    // Wo transpose AFTER attention (WotHi aliases Kf)
    wtrans_split<<<dim3(16, 16), 256, 0, stream>>>(Wo, WotHi, WotLo, 0, 1024, HIDDEN);

    gemm_split<1><<<dim3(HIDDEN / 128, M / 64), 256, 0, stream>>>(
        CtxHi, CtxLo, WotHi, WotLo, bo, nullptr, nullptr, (void*)out, M, HIDDEN, HIDDEN);
}

// Round 9
// 197.934 us; speedup vs baseline: 1.7132x; 1.2189x over previous
//
#include <hip/hip_runtime.h>
#include <hip/hip_bf16.h>

#define HIDDEN 1024
#define NHEAD 16
#define NKV 4
#define HDIM 64
#define KVDIM 256
#define SEQ 2048
#define BATCH 2
#define NQKV 1536   // 1024 (Q) + 256 (K) + 256 (V)

typedef __attribute__((ext_vector_type(4)))  float f32x4;
typedef __attribute__((ext_vector_type(16))) float f32x16;
typedef __attribute__((ext_vector_type(8)))  short s16x8;
typedef __attribute__((ext_vector_type(4)))  short s16x4;

#if defined(__has_builtin)
#if __has_builtin(__builtin_amdgcn_exp2f)
#define EXP2F(x) __builtin_amdgcn_exp2f(x)
#else
#define EXP2F(x) exp2f(x)
#endif
#else
#define EXP2F(x) exp2f(x)
#endif

static __device__ __forceinline__ ushort f2bf(float f) {
    union { __hip_bfloat16 b; ushort u; } cv; cv.b = __float2bfloat16(f); return cv.u;
}
// pack two positive finite f32 into (lo,hi) bf16 pair, round-half-up
static __device__ __forceinline__ unsigned pack_rh2(float a, float b) {
    unsigned ua = __float_as_uint(a) + 0x8000u;
    unsigned ub = __float_as_uint(b) + 0x8000u;
    return (ua >> 16) | (ub & 0xFFFF0000u);
}
// async global->LDS, 16B per lane. LDS dest = wave-uniform base + lane*16.
static __device__ __forceinline__ void async16(const void* g, void* l) {
    __builtin_amdgcn_global_load_lds((__attribute__((address_space(1))) void*)g,
                                     (__attribute__((address_space(3))) void*)l, 16, 0, 0);
}

// ---------------------------------------------------------------------------
// X fp32 -> bf16 (RNE), elementwise. (lo plane no longer needed: plain-bf16
// GEMMs suffice at this problem's operand scales — see error analysis.)
// ---------------------------------------------------------------------------
__global__ __launch_bounds__(256)
void cvt_x(const float* __restrict__ in, ushort* __restrict__ out)
{
    int i = blockIdx.x * 256 + threadIdx.x;
    float4 v = ((const float4*)in)[i];
    ushort4 o;
    o.x = f2bf(v.x); o.y = f2bf(v.y); o.z = f2bf(v.z); o.w = f2bf(v.w);
    ((ushort4*)out)[i] = o;
}

// ---------------------------------------------------------------------------
// Fused Wq/Wk/Wv transpose: W [K][N] fp32 -> T[roff+n][k] bf16 (single plane).
// Grid (24,16): bx<16 -> Wq, bx in [16,20) -> Wk, else Wv (wave-uniform branch).
// ---------------------------------------------------------------------------
__global__ __launch_bounds__(256)
void wtrans_qkv(const float* __restrict__ Wq, const float* __restrict__ Wk,
                const float* __restrict__ Wv, ushort* __restrict__ T)
{
    __shared__ float Tl[64][65];
    const int bx = blockIdx.x, k0 = blockIdx.y * 64;
    const float* W; int N, n0, roff;
    if (bx < 16)      { W = Wq; N = 1024; n0 = bx * 64;        roff = 0; }
    else if (bx < 20) { W = Wk; N = 256;  n0 = (bx - 16) * 64; roff = 1024; }
    else              { W = Wv; N = 256;  n0 = (bx - 20) * 64; roff = 1280; }
    const int tid = threadIdx.x;
#pragma unroll
    for (int it = 0; it < 4; it++) {
        int idx = tid + it * 256;
        int kk = idx >> 4, n4 = (idx & 15) * 4;
        float4 v = *(const float4*)(W + (size_t)(k0 + kk) * N + n0 + n4);
        Tl[kk][n4 + 0] = v.x; Tl[kk][n4 + 1] = v.y;
        Tl[kk][n4 + 2] = v.z; Tl[kk][n4 + 3] = v.w;
    }
    __syncthreads();
#pragma unroll
    for (int it = 0; it < 4; it++) {
        int idx = tid + it * 256;
        int n = idx >> 4, k4 = (idx & 15) * 4;
        ushort4 h4;
        h4.x = f2bf(Tl[k4 + 0][n]); h4.y = f2bf(Tl[k4 + 1][n]);
        h4.z = f2bf(Tl[k4 + 2][n]); h4.w = f2bf(Tl[k4 + 3][n]);
        *(ushort4*)(T + (size_t)(roff + n0 + n) * HIDDEN + k0 + k4) = h4;
    }
}

// ---------------------------------------------------------------------------
// Single-matrix transpose (Wo): W [K][N] fp32 -> T[n][k] bf16.
// ---------------------------------------------------------------------------
__global__ __launch_bounds__(256)
void wtrans_one(const float* __restrict__ W, ushort* __restrict__ T,
                int N, int K)
{
    __shared__ float Tl[64][65];
    const int n0 = blockIdx.x * 64, k0 = blockIdx.y * 64;
    const int tid = threadIdx.x;
#pragma unroll
    for (int it = 0; it < 4; it++) {
        int idx = tid + it * 256;
        int kk = idx >> 4, n4 = (idx & 15) * 4;
        float4 v = *(const float4*)(W + (size_t)(k0 + kk) * N + n0 + n4);
        Tl[kk][n4 + 0] = v.x; Tl[kk][n4 + 1] = v.y;
        Tl[kk][n4 + 2] = v.z; Tl[kk][n4 + 3] = v.w;
    }
    __syncthreads();
#pragma unroll
    for (int it = 0; it < 4; it++) {
        int idx = tid + it * 256;
        int n = idx >> 4, k4 = (idx & 15) * 4;
        ushort4 h4;
        h4.x = f2bf(Tl[k4 + 0][n]); h4.y = f2bf(Tl[k4 + 1][n]);
        h4.z = f2bf(Tl[k4 + 2][n]); h4.w = f2bf(Tl[k4 + 3][n]);
        *(ushort4*)(T + (size_t)(n0 + n) * K + k0 + k4) = h4;
    }
}

// ---------------------------------------------------------------------------
// Plain-bf16 MFMA GEMM (1-term), fp32 accumulate: C = A[M,K] @ B^T[N,K] + bias.
// 64x128 tile (M x N), BK=32, 4 waves 2x2; per wave 2x4 grid of 16x16x32.
// Error analysis (this problem's scales): QKV GEMM operand-rounding error
// ~2.5e-3 on q~0.64 is contracted by softmax-averaging to ~7e-5 in ctx;
// O-proj error ~3.5e-5 (ctx~0.014, Wo~0.02). Both << 1.07e-3 threshold.
// MODE 0: bf16 out (QKV; Q cols scaled 0.125*log2e). MODE 1: fp32 out.
// ---------------------------------------------------------------------------
template <int MODE>
__global__ __launch_bounds__(256)
void gemm_bf(const ushort* __restrict__ A, const ushort* __restrict__ Bt,
             const float* __restrict__ b0, const float* __restrict__ b1,
             const float* __restrict__ b2, void* __restrict__ Cout,
             int M, int N, int K)
{
    __shared__ __align__(16) ushort Ah[64 * 32];
    __shared__ __align__(16) ushort Bh[128 * 32];

    const int tid = threadIdx.x;
    const int lane = tid & 63, wv = tid >> 6;
    const int wr = wv >> 1, wc = wv & 1;
    const int m = lane & 15, c = lane >> 4;
    const int row0 = blockIdx.y * 64, col0 = blockIdx.x * 128;

    // A staging: 1 slot/thread (64 rows x 32 cols)
    const ushort* gA = A + (size_t)(row0 + (tid >> 2)) * K + (tid & 3) * 8;
    const int ldsA = tid * 8;
    // B staging: 2 slots/thread (128 rows x 32 cols)
    const ushort* gB[2]; int ldsB[2];
#pragma unroll
    for (int it = 0; it < 2; it++) {
        int idx = it * 256 + tid;
        gB[it] = Bt + (size_t)(col0 + (idx >> 2)) * K + (idx & 3) * 8;
        ldsB[it] = idx * 8;
    }

    f32x4 acc[2][4];
#pragma unroll
    for (int t = 0; t < 2; t++)
#pragma unroll
        for (int u = 0; u < 4; u++) acc[t][u] = (f32x4){0.f, 0.f, 0.f, 0.f};

    for (int k0 = 0; k0 < K; k0 += 32) {
        __syncthreads();
        async16(gA + k0, Ah + ldsA);
#pragma unroll
        for (int it = 0; it < 2; it++) async16(gB[it] + k0, Bh + ldsB[it]);
        __syncthreads();

        s16x8 ah[2], bh[4];
#pragma unroll
        for (int t = 0; t < 2; t++)
            ah[t] = *(const s16x8*)&Ah[(wr * 32 + t * 16 + m) * 32 + c * 8];
#pragma unroll
        for (int u = 0; u < 4; u++)
            bh[u] = *(const s16x8*)&Bh[(wc * 64 + u * 16 + m) * 32 + c * 8];
#pragma unroll
        for (int t = 0; t < 2; t++)
#pragma unroll
            for (int u = 0; u < 4; u++)
                acc[t][u] = __builtin_amdgcn_mfma_f32_16x16x32_bf16(ah[t], bh[u], acc[t][u], 0, 0, 0);
    }

    const int orow = row0 + wr * 32 + 4 * c;   // + 16t + r
    const int ocol = col0 + wc * 64 + m;       // + 16u
    if (MODE == 0) {
        ushort* Cb = (ushort*)Cout;
#pragma unroll
        for (int u = 0; u < 4; u++) {
            int n = ocol + 16 * u;
            float bias, scl;
            if (n < 1024)      { bias = b0[n];        scl = 0.18033688f; }  // 0.125*log2(e)
            else if (n < 1280) { bias = b1[n - 1024]; scl = 1.0f; }
            else               { bias = b2[n - 1280]; scl = 1.0f; }
#pragma unroll
            for (int t = 0; t < 2; t++)
#pragma unroll
                for (int r = 0; r < 4; r++)
                    Cb[(size_t)(orow + 16 * t + r) * N + n] = f2bf((acc[t][u][r] + bias) * scl);
        }
    } else {
        float* Cf = (float*)Cout;
#pragma unroll
        for (int u = 0; u < 4; u++) {
            int n = ocol + 16 * u;
            float bias = b0[n];
#pragma unroll
            for (int t = 0; t < 2; t++)
#pragma unroll
                for (int r = 0; r < 4; r++)
                    Cf[(size_t)(orow + 16 * t + r) * N + n] = acc[t][u][r] + bias;
        }
    }
}

// ---------------------------------------------------------------------------
// Pack K and V (bf16 cols of QKV) into fragment-major buffers (unchanged).
// ---------------------------------------------------------------------------
__global__ __launch_bounds__(256)
void kvpack(const ushort* __restrict__ QKV, ushort* __restrict__ Kf,
            ushort* __restrict__ Vf)
{
    __shared__ __align__(16) ushort Kt[64][72];
    __shared__ __align__(16) ushort Vt[64][72];
    const int kt = blockIdx.x, hk = blockIdx.y, b = blockIdx.z;
    const int tid = threadIdx.x;

#pragma unroll
    for (int it = 0; it < 2; it++) {
        int idx = tid + it * 256;
        int r = idx >> 3, c8 = (idx & 7) * 8;
        const ushort* src = QKV + (size_t)(b * SEQ + kt * 64 + r) * NQKV + hk * HDIM + c8;
        *(s16x8*)&Kt[r][c8] = *(const s16x8*)(src + 1024);
        *(s16x8*)&Vt[r][c8] = *(const s16x8*)(src + 1280);
    }
    __syncthreads();

#pragma unroll
    for (int it = 0; it < 2; it++) {
        int idx = tid + it * 256;
        int t32 = idx >> 8, kc = (idx >> 6) & 3, lane = idx & 63;
        int n32 = lane & 31, h5 = lane >> 5;
        s16x8 fr = *(const s16x8*)&Kt[t32 * 32 + n32][kc * 16 + h5 * 8];
        size_t flat = ((size_t)(((b * NKV + hk) * 64 + kt * 2 + t32) * 4 + kc) * 64 + lane) * 8;
        *(s16x8*)(Kf + flat) = fr;
    }
#pragma unroll
    for (int it = 0; it < 2; it++) {
        int idx = tid + it * 256;
        int kcdn = idx >> 6, lane = idx & 63;
        int kc = kcdn >> 1, dn = kcdn & 1;
        int n32 = lane & 31, h5 = lane >> 5;
        s16x8 fr;
#pragma unroll
        for (int j = 0; j < 8; j++)
            fr[j] = (short)Vt[kc * 16 + h5 * 8 + j][dn * 32 + n32];
        size_t flat = ((size_t)(((b * NKV + hk) * 32 + kt) * 8 + kc * 2 + dn) * 64 + lane) * 8;
        *(s16x8*)(Vf + flat) = fr;
    }
}

// ---------------------------------------------------------------------------
// Flash attention v7 = v6 (S^T layout, stride-68 Ps, ones-MFMA l, depth-1
// pipeline) with a single-plane bf16 ctx output (O-proj is now plain bf16).
// ---------------------------------------------------------------------------
__global__ __launch_bounds__(512, 2)
void attn_mfma7(const ushort* __restrict__ QKV, const ushort* __restrict__ Kf,
                const ushort* __restrict__ Vf, ushort* __restrict__ Chi)
{
    __shared__ __align__(16) ushort Ps[8][32][68];   // 34,816 B; merge bufs alias
    float* OLb = (float*)&Ps[0][0][0];               // [4][32][64] = 32,768 B
    float* LLb = (float*)((char*)&Ps[0][0][0] + 33024);  // [4][32]

    const int tid = threadIdx.x, w = tid >> 6, lane = tid & 63;
    const int g = w >> 2, ws_ = w & 3;               // q-group, kt-split index
    const int n32 = lane & 31, h5 = lane >> 5;
    const int h = blockIdx.y, b = blockIdx.z, hk = h >> 2;
    const int q0 = blockIdx.x * 64 + g * 32;

    // Q B-fragments (4 k-chunks of 16), hoisted
    const ushort* qrow = QKV + (size_t)(b * SEQ + q0 + n32) * NQKV + h * HDIM + h5 * 8;
    s16x8 aq[4];
#pragma unroll
    for (int kc = 0; kc < 4; kc++) aq[kc] = *(const s16x8*)(qrow + kc * 16);

    f32x16 accO[2], accl;
#pragma unroll
    for (int j = 0; j < 16; j++) { accO[0][j] = 0.f; accO[1][j] = 0.f; accl[j] = 0.f; }

    s16x8 ones;
#pragma unroll
    for (int j = 0; j < 8; j++) ones[j] = (short)0x3F80;   // bf16 1.0

    const ushort* kf0 = Kf + (size_t)(b * NKV + hk) * (64 * 4 * 64 * 8) + (size_t)lane * 8;
    const ushort* vf0 = Vf + (size_t)(b * NKV + hk) * (32 * 8 * 64 * 8) + (size_t)lane * 8;

    s16x8 kreg[8], vreg[8];

#define LOAD_K(kt_) do {                                                      \
    _Pragma("unroll")                                                         \
    for (int kn = 0; kn < 2; kn++)                                            \
        _Pragma("unroll")                                                     \
        for (int kc = 0; kc < 4; kc++)                                        \
            kreg[kn * 4 + kc] =                                               \
                *(const s16x8*)(kf0 + (size_t)(((kt_) * 2 + kn) * 4 + kc) * 512); \
} while (0)

#define LOAD_V(kt_) do {                                                      \
    _Pragma("unroll")                                                         \
    for (int kc = 0; kc < 4; kc++)                                            \
        _Pragma("unroll")                                                     \
        for (int dn = 0; dn < 2; dn++)                                        \
            vreg[kc * 2 + dn] =                                               \
                *(const s16x8*)(vf0 + (size_t)((kt_) * 8 + kc * 2 + dn) * 512); \
} while (0)

// S^T = K Q^T: lane owns q=n32; key(reg) = kn*32 + (reg&3) + 8*(reg>>2) + 4*h5.
// exp2 in log2 domain (log2e folded into Q), packed b64 stores.
#define QK_EXP_STORE() do {                                                   \
    _Pragma("unroll")                                                         \
    for (int kn = 0; kn < 2; kn++) {                                          \
        f32x16 S;                                                             \
        _Pragma("unroll")                                                     \
        for (int j = 0; j < 16; j++) S[j] = 0.f;                              \
        _Pragma("unroll")                                                     \
        for (int kc = 0; kc < 4; kc++)                                        \
            S = __builtin_amdgcn_mfma_f32_32x32x16_bf16(kreg[kn * 4 + kc],    \
                    aq[kc], S, 0, 0, 0);                                      \
        float p[16];                                                          \
        _Pragma("unroll")                                                     \
        for (int reg = 0; reg < 16; reg++) p[reg] = EXP2F(S[reg]);            \
        _Pragma("unroll")                                                     \
        for (int t = 0; t < 4; t++) {                                         \
            uint2 pk;                                                         \
            pk.x = pack_rh2(p[4 * t + 0], p[4 * t + 1]);                      \
            pk.y = pack_rh2(p[4 * t + 2], p[4 * t + 3]);                      \
            *(uint2*)&Ps[w][n32][kn * 32 + 8 * t + 4 * h5] = pk;              \
        }                                                                     \
    }                                                                         \
} while (0)

#define PV_STEP() do {                                                        \
    s16x8 pa[4];                                                              \
    _Pragma("unroll")                                                         \
    for (int kc = 0; kc < 4; kc++) {                                          \
        s16x4 lo4 = *(const s16x4*)&Ps[w][n32][kc * 16 + h5 * 8];             \
        s16x4 hi4 = *(const s16x4*)&Ps[w][n32][kc * 16 + h5 * 8 + 4];         \
        pa[kc] = __builtin_shufflevector(lo4, hi4, 0, 1, 2, 3, 4, 5, 6, 7);   \
    }                                                                         \
    _Pragma("unroll")                                                         \
    for (int kc = 0; kc < 4; kc++) {                                          \
        accl = __builtin_amdgcn_mfma_f32_32x32x16_bf16(pa[kc], ones, accl, 0, 0, 0); \
        _Pragma("unroll")                                                     \
        for (int dn = 0; dn < 2; dn++)                                        \
            accO[dn] = __builtin_amdgcn_mfma_f32_32x32x16_bf16(pa[kc],        \
                           vreg[kc * 2 + dn], accO[dn], 0, 0, 0);             \
    }                                                                         \
} while (0)

    // prologue: first tile's scores
    LOAD_K(ws_);
    QK_EXP_STORE();

    for (int i = 1; i < 8; i++) {
        const int ktc = ws_ + 4 * i;
        LOAD_V(ktc - 4);     // V for previous tile (issued first: partial vm wait)
        LOAD_K(ktc);         // K for current tile
        PV_STEP();           // PV(prev): reads Ps BEFORE the writes below (in-order DS)
        QK_EXP_STORE();      // scores(cur) + overwrite Ps
    }

    // epilogue: last tile's PV
    LOAD_V(ws_ + 28);
    PV_STEP();

#undef LOAD_K
#undef LOAD_V
#undef QK_EXP_STORE
#undef PV_STEP

    __syncthreads();   // everyone done with Ps — safe to alias merge buffers

    const int qq = tid >> 4;          // 0..31
    const int d0 = (tid & 15) * 4;    // 0..60
#pragma unroll
    for (int phase = 0; phase < 2; phase++) {
        if (g == phase) {
#pragma unroll
            for (int reg = 0; reg < 16; reg++) {
                int q = (reg & 3) + 8 * (reg >> 2) + 4 * h5;
                OLb[(ws_ * 32 + q) * 64 + n32]      = accO[0][reg];
                OLb[(ws_ * 32 + q) * 64 + 32 + n32] = accO[1][reg];
                if (n32 == 0) LLb[ws_ * 32 + q] = accl[reg];
            }
        }
        __syncthreads();
        {
            float lsum = LLb[qq] + LLb[32 + qq] + LLb[64 + qq] + LLb[96 + qq];
            float inv = 1.f / lsum;
            ushort4 hs;
            float o0 = (OLb[(0 * 32 + qq) * 64 + d0 + 0] + OLb[(1 * 32 + qq) * 64 + d0 + 0] +
                        OLb[(2 * 32 + qq) * 64 + d0 + 0] + OLb[(3 * 32 + qq) * 64 + d0 + 0]) * inv;
            float o1 = (OLb[(0 * 32 + qq) * 64 + d0 + 1] + OLb[(1 * 32 + qq) * 64 + d0 + 1] +
                        OLb[(2 * 32 + qq) * 64 + d0 + 1] + OLb[(3 * 32 + qq) * 64 + d0 + 1]) * inv;
            float o2 = (OLb[(0 * 32 + qq) * 64 + d0 + 2] + OLb[(1 * 32 + qq) * 64 + d0 + 2] +
                        OLb[(2 * 32 + qq) * 64 + d0 + 2] + OLb[(3 * 32 + qq) * 64 + d0 + 2]) * inv;
            float o3 = (OLb[(0 * 32 + qq) * 64 + d0 + 3] + OLb[(1 * 32 + qq) * 64 + d0 + 3] +
                        OLb[(2 * 32 + qq) * 64 + d0 + 3] + OLb[(3 * 32 + qq) * 64 + d0 + 3]) * inv;
            hs.x = f2bf(o0); hs.y = f2bf(o1); hs.z = f2bf(o2); hs.w = f2bf(o3);
            size_t off = (size_t)(b * SEQ + blockIdx.x * 64 + phase * 32 + qq) * HIDDEN
                       + h * HDIM + d0;
            *(ushort4*)(Chi + off) = hs;
        }
        __syncthreads();   // before next phase overwrites merge buffers
    }
}

// ---------------------------------------------------------------------------
extern "C" void kernel_launch(void* const* d_in, const int* in_sizes, int n_in,
                              void* d_out, int out_size, void* d_ws, size_t ws_size,
                              hipStream_t stream)
{
    const float* X  = (const float*)d_in[0];
    const float* Wq = (const float*)d_in[1];
    const float* bq = (const float*)d_in[2];
    const float* Wk = (const float*)d_in[3];
    const float* bk = (const float*)d_in[4];
    const float* Wv = (const float*)d_in[5];
    const float* bv = (const float*)d_in[6];
    const float* Wo = (const float*)d_in[7];
    const float* bo = (const float*)d_in[8];
    float* out = (float*)d_out;

    const int M = BATCH * SEQ;  // 4096
    // ws layout (37 MB): Xb 8 | Ctx 8 | QKVb 12 | Wqkvt 3 | Wot 2 | Kf 2 | Vf 2
    char* ws = (char*)d_ws;
    ushort* Xb    = (ushort*)(ws);
    ushort* Ctx   = (ushort*)(ws + (8u  << 20));
    ushort* QKVb  = (ushort*)(ws + (16u << 20));
    ushort* Wqkvt = (ushort*)(ws + (28u << 20));
    ushort* Wot   = (ushort*)(ws + (31u << 20));
    ushort* Kf    = (ushort*)(ws + (33u << 20));
    ushort* Vf    = (ushort*)(ws + (35u << 20));

    cvt_x<<<dim3(M * HIDDEN / 4 / 256), 256, 0, stream>>>(X, Xb);
    wtrans_qkv<<<dim3(24, 16), 256, 0, stream>>>(Wq, Wk, Wv, Wqkvt);
    wtrans_one<<<dim3(16, 16), 256, 0, stream>>>(Wo, Wot, 1024, HIDDEN);

    gemm_bf<0><<<dim3(NQKV / 128, M / 64), 256, 0, stream>>>(
        Xb, Wqkvt, bq, bk, bv, (void*)QKVb, M, NQKV, HIDDEN);

    kvpack<<<dim3(SEQ / 64, NKV, BATCH), 256, 0, stream>>>(QKVb, Kf, Vf);

    attn_mfma7<<<dim3(SEQ / 64, NHEAD, BATCH), 512, 0, stream>>>(QKVb, Kf, Vf, Ctx);

    gemm_bf<1><<<dim3(HIDDEN / 128, M / 64), 256, 0, stream>>>(
        Ctx, Wot, bo, nullptr, nullptr, (void*)out, M, HIDDEN, HIDDEN);
}